// Round 8
// baseline (360.303 us; speedup 1.0000x reference)
//
#include <hip/hip_runtime.h>
#include <hip/hip_bf16.h>
#include <type_traits>

using bf16 = __hip_bfloat16;
typedef __attribute__((ext_vector_type(8))) short bf16x8;   // 8 bf16 (4 VGPRs) — MFMA A/B frag
typedef __attribute__((ext_vector_type(4))) float floatx4;  // MFMA C/D frag

static constexpr int Bb = 2, S = 4096, D = 768, H = 6, HK = 2, HD = 128, REP = 3;
static constexpr int M_ROWS = Bb * S;   // 8192
static constexpr int NQKV = 1280;       // fused projection width: 768 Q + 256 K + 256 V

__device__ __forceinline__ floatx4 mfma16(bf16x8 a, bf16x8 b, floatx4 c) {
  return __builtin_amdgcn_mfma_f32_16x16x32_bf16(a, b, c, 0, 0, 0);
}

// async global->LDS, 16B/lane; LDS dest = wave-uniform base + lane*16
__device__ __forceinline__ void gld_lds16(const bf16* g, bf16* l) {
  __builtin_amdgcn_global_load_lds(
      (const __attribute__((address_space(1))) unsigned int*)g,
      (__attribute__((address_space(3))) unsigned int*)l, 16, 0, 0);
}

#if defined(__has_builtin)
#if __has_builtin(__builtin_amdgcn_exp2f)
#define EXP2F(x) __builtin_amdgcn_exp2f(x)
#endif
#endif
#ifndef EXP2F
#define EXP2F(x) exp2f(x)
#endif

// pack two fp32 -> 2x bf16 (round-half-up): bias + one v_perm_b32
__device__ __forceinline__ unsigned pk2(float a, float b) {
  unsigned ua = __builtin_bit_cast(unsigned, a) + 0x8000u;
  unsigned ub = __builtin_bit_cast(unsigned, b) + 0x8000u;
#if defined(__has_builtin) && __has_builtin(__builtin_amdgcn_perm)
  return __builtin_amdgcn_perm(ub, ua, 0x07060302);  // {ub.hi16, ua.hi16}
#else
  return (ua >> 16) | (ub & 0xffff0000u);
#endif
}

// gfx950 cross-lane half-swaps (register-only, VALU pipe — no LDS, no waitcnt):
// perm32swap(a,b): a' = [a.q0,a.q1,b.q0,b.q1], b' = [a.q2,a.q3,b.q2,b.q3]   (by 16-lane quads)
// perm16swap(a,b): a' = [a.q0,b.q0,a.q2,b.q2], b' = [a.q1,b.q1,a.q3,b.q3]
__device__ __forceinline__ void perm32swap(unsigned& a, unsigned& b) {
  asm volatile("v_permlane32_swap_b32 %0, %1" : "+v"(a), "+v"(b));
}
__device__ __forceinline__ void perm16swap(unsigned& a, unsigned& b) {
  asm volatile("v_permlane16_swap_b32 %0, %1" : "+v"(a), "+v"(b));
}

// ---------------- fp32 -> bf16 convert, WEIGHTS ONLY ----------------
// R8: x conversion fused into gemm_qkv A-staging; this kernel now only converts the
// 1.57M weight elements (~2us) instead of 7.9M.
static constexpr size_t W_WQ = (size_t)H * HD * D;          // 589824
static constexpr size_t W_WK = W_WQ + (size_t)HK * HD * D;  // 786432
static constexpr size_t W_WV = W_WK + (size_t)HK * HD * D;  // 983040
static constexpr size_t W_WO = W_WV + (size_t)D * H * HD;   // 1572864

__global__ __launch_bounds__(256) void cvt_w(const float* __restrict__ wq,
                                             const float* __restrict__ wk,
                                             const float* __restrict__ wv,
                                             const float* __restrict__ wo,
                                             bf16* __restrict__ wqkvb,
                                             bf16* __restrict__ wob, float qscale) {
  size_t i = ((size_t)blockIdx.x * 256 + threadIdx.x) * 4;
  const float* src;
  bf16* dst;
  float s = 1.f;
  size_t off;
  if (i < W_WQ)       { src = wq; dst = wqkvb;              off = i; s = qscale; }
  else if (i < W_WK)  { src = wk; dst = wqkvb + 589824;     off = i - W_WQ; }
  else if (i < W_WV)  { src = wv; dst = wqkvb + 786432;     off = i - W_WK; }
  else                { src = wo; dst = wob;                off = i - W_WV; }
  float4 v = *(const float4*)(src + off);
  uint2 st;
  st.x = pk2(v.x * s, v.y * s);
  st.y = pk2(v.z * s, v.w * s);
  *(uint2*)(dst + off) = st;
}

// ---------------- fused QKV projection GEMM: f32-A reg-staging + dual epilogue ------------
// C[M,N] = cvt(X)[M,K] @ W[N,K]^T. 128x128 tile, BK=64, single 640-block launch.
// R8: A is staged from FP32 x directly (reg-stage: 8x float4 load -> pk2 -> 4x ds_write_b128
// into the same XOR-swizzled layout; write-side swizzle is legal with ds_write). The x->bf16
// HBM round-trip (25MB read + 12.5MB write + 12.5MB re-read) and cvt serialization vanish.
// A-load issue is placed AFTER the pre-compute barrier so the L2 latency drains at the
// POST-compute barrier (hidden under 32 MFMAs) — not exposed at the staging barrier.
// W staging stays global_load_lds (bf16 from cvt_w).
// Dual epilogue (R7, kept): n0<1024 Q/K swapped-MFMA + packed uint2 stores; n0>=1024 V ->
// verified LDS-transpose -> Vt[b][g][d][t]. Values bit-identical to the reference chain.
// Dispatch note: bid = m + 64*n -> same-m blocks land on the SAME XCD -> x f32 panel
// re-reads (10 n-tiles) are L2-local. No XCD swizzle.
__global__ __launch_bounds__(256, 3) void gemm_qkv(const float* __restrict__ X,
                                                   const bf16* __restrict__ W,
                                                   bf16* __restrict__ C,
                                                   bf16* __restrict__ Vt,
                                                   int M, int N, int K) {
  const int tid = threadIdx.x;
  const int wave = tid >> 6, lane = tid & 63;
  const int quad = lane >> 4, lq = lane & 15;
  const int m0 = blockIdx.x * 128, n0 = blockIdx.y * 128;
  const int wm = (wave & 1) * 64, wn = (wave >> 1) * 64;

  __shared__ __align__(16) bf16 As[128 * 64];  // 16 KB
  __shared__ __align__(16) bf16 Ws[128 * 64];  // 16 KB

  floatx4 acc[4][4] = {};

  const int srow = lane >> 3, sc = lane & 7;   // W staging: 8 rows x 8 chunks per issue
  const int ar = tid >> 1, cb = (tid & 1) * 4; // A staging: row + chunk-quad ownership

  const float* Ag = X + (size_t)(m0 + ar) * K + (tid & 1) * 32;

  float4 pf[8];
  auto loadA = [&](int k0) {
#pragma unroll
    for (int j = 0; j < 8; ++j) pf[j] = *(const float4*)(Ag + k0 + j * 4);
  };
  auto writeA = [&]() {
#pragma unroll
    for (int t = 0; t < 4; ++t) {
      int c = cb + t;
      uint4 st;
      st.x = pk2(pf[2 * t].x, pf[2 * t].y);
      st.y = pk2(pf[2 * t].z, pf[2 * t].w);
      st.z = pk2(pf[2 * t + 1].x, pf[2 * t + 1].y);
      st.w = pk2(pf[2 * t + 1].z, pf[2 * t + 1].w);
      *(uint4*)&As[ar * 64 + ((c ^ (ar & 7)) * 8)] = st;
    }
  };
  auto stageW = [&](int k0) {
#pragma unroll
    for (int i = 0; i < 4; ++i) {
      int ig = wave * 4 + i;               // 0..15
      int r = ig * 8 + srow;               // 0..127
      int c = sc ^ (r & 7);
      gld_lds16(&W[(size_t)(n0 + r) * K + k0 + c * 8], &Ws[ig * 512]);
    }
  };

  loadA(0);  // prologue (latency exposed once)

  const bool qk = (n0 < 1024);
  for (int k0 = 0; k0 < K; k0 += 64) {
    writeA();        // A(k) regs -> LDS (lgkm)
    stageW(k0);      // W(k) DMA (vm)
    __syncthreads(); // drains both; prior compute finished at previous barrier
    if (k0 + 64 < K) loadA(k0 + 64);  // issue now; drains at POST-compute barrier (hidden)
#pragma unroll
    for (int kh = 0; kh < 2; ++kh) {
      bf16x8 af[4], wf[4];
#pragma unroll
      for (int i = 0; i < 4; ++i) {
        int ra = wm + i * 16 + lq, rw = wn + i * 16 + lq;
        af[i] = *(const bf16x8*)&As[ra * 64 + (((kh * 4 + quad) ^ (ra & 7)) * 8)];
        wf[i] = *(const bf16x8*)&Ws[rw * 64 + (((kh * 4 + quad) ^ (rw & 7)) * 8)];
      }
      if (qk) {
#pragma unroll
        for (int i = 0; i < 4; ++i)
#pragma unroll
          for (int j = 0; j < 4; ++j) acc[i][j] = mfma16(wf[j], af[i], acc[i][j]);  // swapped
      } else {
#pragma unroll
        for (int i = 0; i < 4; ++i)
#pragma unroll
          for (int j = 0; j < 4; ++j) acc[i][j] = mfma16(af[i], wf[j], acc[i][j]);
      }
    }
    __syncthreads();
  }

  if (qk) {
    // packed epilogue: lane(quad,lq) -> row m0+wm+i*16+lq, cols n0+wn+j*16+quad*4 .. +3
#pragma unroll
    for (int i = 0; i < 4; ++i)
#pragma unroll
      for (int j = 0; j < 4; ++j) {
        uint2 st;
        st.x = pk2(acc[i][j][0], acc[i][j][1]);
        st.y = pk2(acc[i][j][2], acc[i][j][3]);
        int row = m0 + wm + i * 16 + lq;
        int col = n0 + wn + j * 16 + quad * 4;
        *(uint2*)&C[(size_t)row * N + col] = st;
      }
    return;
  }

  // V path: col-XOR-swizzled LDS transpose, then coalesced b128 stores to Vt[b][g][d][t]
  bf16* tb = (wave < 2 ? As : Ws) + (wave & 1) * 4096;
  char* tc = (char*)tb;
#pragma unroll
  for (int i = 0; i < 4; ++i)
#pragma unroll
    for (int j = 0; j < 4; ++j) {
      uint2 st;
      st.x = pk2(acc[i][j][0], acc[i][j][1]);
      st.y = pk2(acc[i][j][2], acc[i][j][3]);
      int col = j * 16 + lq;
      int cc = (i * 2 + (quad >> 1)) ^ (col & 7);
      *(uint2*)(tc + col * 128 + cc * 16 + (quad & 1) * 8) = st;
    }
  const int b = m0 >> 12;  // uniform per block (128-row tiles never cross S)
  const int dd_off = lane >> 3, schunk = lane & 7;
  const int sbase = (m0 & 4095) + wm + schunk * 8;
#pragma unroll
  for (int e = 0; e < 8; ++e) {
    int cl = e * 8 + dd_off;                      // local col 0..63
    int col = (n0 - 1024) + wn + cl;              // 0..255
    int gg = col >> 7, dd = col & 127;
    bf16x8 vv = *(const bf16x8*)(tc + cl * 128 + ((schunk ^ (cl & 7)) * 16));
    *(bf16x8*)&Vt[((size_t)(b * HK + gg) * HD + dd) * S + sbase] = vv;
  }
}

// ---------------- out-projection GEMM: 128x64 tile, swapped operands + float4 stores ----------------
// 128x64 tiles -> 768 blocks = exactly 3/CU x 256 CUs, 12 waves/CU, single full round.
// Swapped-operand MFMA -> lane holds 4 row-contiguous f32 -> one 16B store per tile.
__global__ __launch_bounds__(256, 3) void gemm_out(const bf16* __restrict__ A,
                                                   const bf16* __restrict__ W,
                                                   float* __restrict__ C,
                                                   int M, int N, int K) {
  const int tid = threadIdx.x;
  const int wave = tid >> 6, lane = tid & 63;
  const int quad = lane >> 4, lq = lane & 15;
  const int m0 = blockIdx.x * 128, n0 = blockIdx.y * 64;
  const int wm = (wave & 1) * 64, wn = (wave >> 1) * 32;

  __shared__ __align__(16) bf16 As[128 * 64];  // 16 KB
  __shared__ __align__(16) bf16 Ws[64 * 64];   // 8 KB

  floatx4 acc[4][2] = {};

  const int srow = lane >> 3, sc = lane & 7;  // staging: 8 rows x 8 chunks per issue

  for (int k0 = 0; k0 < K; k0 += 64) {
#pragma unroll
    for (int i = 0; i < 4; ++i) {
      int ig = wave * 4 + i;               // 0..15
      int r = ig * 8 + srow;               // 0..127
      int c = sc ^ (r & 7);
      gld_lds16(&A[(size_t)(m0 + r) * K + k0 + c * 8], &As[ig * 512]);
    }
#pragma unroll
    for (int i = 0; i < 2; ++i) {
      int ig = wave * 2 + i;               // 0..7
      int r = ig * 8 + srow;               // 0..63
      int c = sc ^ (r & 7);
      gld_lds16(&W[(size_t)(n0 + r) * K + k0 + c * 8], &Ws[ig * 512]);
    }
    __syncthreads();
#pragma unroll
    for (int kh = 0; kh < 2; ++kh) {
      bf16x8 af[4], wf[2];
#pragma unroll
      for (int i = 0; i < 4; ++i) {
        int ra = wm + i * 16 + lq;
        af[i] = *(const bf16x8*)&As[ra * 64 + (((kh * 4 + quad) ^ (ra & 7)) * 8)];
      }
#pragma unroll
      for (int j = 0; j < 2; ++j) {
        int rw = wn + j * 16 + lq;
        wf[j] = *(const bf16x8*)&Ws[rw * 64 + (((kh * 4 + quad) ^ (rw & 7)) * 8)];
      }
#pragma unroll
      for (int i = 0; i < 4; ++i)
#pragma unroll
        for (int j = 0; j < 2; ++j) acc[i][j] = mfma16(wf[j], af[i], acc[i][j]);  // swapped
    }
    __syncthreads();
  }
#pragma unroll
  for (int i = 0; i < 4; ++i)
#pragma unroll
    for (int j = 0; j < 2; ++j) {
      int row = m0 + wm + i * 16 + lq;
      int col = n0 + wn + j * 16 + quad * 4;
      *(floatx4*)&C[(size_t)row * N + col] = acc[i][j];
    }
}

// ---------------- Flash attention: S-transposed, no-max softmax, intra-block split-K ----------------
// R3 BEST-KNOWN-GOOD (~110-115 us, ~920 TF effective): LDS DMA K dbuf + V 3-buf, deferred-PV,
// in-register P^T transpose, 1 barrier/iter, 4-wave blocks, 2 blocks/CU (8 waves/CU).
// Bracketing of this plateau (keep for posterity):
//   R0 setprio: ~0.  R1 in-reg transpose: +8% (conflicts 3.15M->0).  R2/R3 deferred-PV: ~0
//   (both MFMA pools share one matrix pipe).  R4 2-wave blocks: -35% (4 waves/CU: perf is
//   ~linear in waves/CU; 2048 waves is the structural max for this decomposition).
//   R5 V-from-global PV: -33% (per-wave vmcnt stalls at 2 waves/SIMD — same mode as r8;
//   LDS DMA is the only latency structure that works at this occupancy).
__global__ __launch_bounds__(256, 2) void flash_attn(const bf16* __restrict__ QKV,
                                                     const bf16* __restrict__ Vt,
                                                     bf16* __restrict__ O) {
  const int bid = blockIdx.x;
  const int bg = (bid & 7) >> 1;                 // 0..3 -> (b,g), XCD-clustered
  const int b = bg >> 1, g = bg & 1;
  const int qt = ((bid >> 3) << 1) | (bid & 1);  // 0..127
  const int q0 = qt * 32;

  const int tid = threadIdx.x;
  const int w = tid >> 6, lane = tid & 63;
  const int half = w >> 1, wp = w & 1;           // KV-half, index within pair
  const int quad = lane >> 4, lq = lane & 15;

  __shared__ __align__(16) char smem[81920];
  bf16* Ks = (bf16*)smem;            // [kbuf 0..1][half][32*128], chunk c at c^(trow&15)
  bf16* Vs = (bf16*)(smem + 32768);  // [vbuf 0..2][half][128*32], chunk c at c^((drow>>1)&3)

  const bf16* Kgh = QKV + (size_t)b * S * NQKV + H * HD + g * HD + (size_t)half * 2048 * NQKV;
  const bf16* Vgh = Vt + (size_t)(b * HK + g) * HD * S + half * 2048;

  auto stage = [&](int t0, int kbuf, int vbuf) {
    bf16* kd = Ks + (kbuf * 2 + half) * 4096;
    bf16* vd = Vs + (vbuf * 2 + half) * 4096;
#pragma unroll
    for (int i = 0; i < 4; ++i) {
      int ig = wp * 4 + i;                 // 0..7
      int tl = ig * 4 + (lane >> 4);       // 0..31
      int c = (lane & 15) ^ (tl & 15);
      gld_lds16(Kgh + (size_t)(t0 + tl) * NQKV + c * 8, kd + ig * 512);
    }
#pragma unroll
    for (int i = 0; i < 4; ++i) {
      int ig = wp * 4 + i;
      int dl = ig * 16 + (lane >> 2);      // 0..127
      int c = (lane & 3) ^ ((dl >> 1) & 3);
      gld_lds16(Vgh + (size_t)dl * S + t0 + c * 8, vd + ig * 512);
    }
  };

  stage(0, 0, 0);  // prologue: tile 0 -> kbuf 0, vbuf 0

  // Q fragments: B-operand layout (n=lane&15 -> q-row, k=quad*8+j -> d)
  const bf16* Qg = QKV + ((size_t)b * S + q0 + wp * 16 + lq) * NQKV + g * REP * HD;
  bf16x8 qf[3][4];
#pragma unroll
  for (int u = 0; u < 3; ++u)
#pragma unroll
    for (int kk = 0; kk < 4; ++kk)
      qf[u][kk] = *(const bf16x8*)(Qg + u * HD + kk * 32 + quad * 8);

  bf16x8 ones;
#pragma unroll
  for (int j = 0; j < 8; ++j) ones[j] = (short)0x3F80;  // bf16 1.0

  floatx4 o[3][8] = {};
  floatx4 lacc[3] = {};           // denominator via ones-MFMA (all regs = row-sum)
  bf16x8 pf_prev[3];              // P^T B-frags of tile it-1 (deferred-PV state)
  const int sw = (lq >> 1) & 3;   // swizzle key (V layout)

#pragma unroll 2
  for (int it = 0; it < 64; ++it) {
    const int kcur = it & 1;
    __syncthreads();  // K/V[it] staged; V[it-1] still intact (3-buf)
    if (it + 1 < 64) stage((it + 1) * 32, kcur ^ 1, (it + 1) % 3);

    const bf16* ks = Ks + (kcur * 2 + half) * 4096;

    // ---- S^T(it) = K Q^T : kf read once, reused by 3 heads ----
    floatx4 sf[3][2] = {};
    __builtin_amdgcn_s_setprio(1);
#pragma unroll
    for (int tt = 0; tt < 2; ++tt)
#pragma unroll
      for (int kk = 0; kk < 4; ++kk) {
        int c = (kk * 4 + quad) ^ lq;  // t row = tt*16+lq -> key lq
        bf16x8 kf = *(const bf16x8*)&ks[(tt * 16 + lq) * 128 + c * 8];
#pragma unroll
        for (int u = 0; u < 3; ++u) sf[u][tt] = mfma16(kf, qf[u][kk], sf[u][tt]);
      }

    // ---- deferred PV(it-1): independent of QK^T(it) above -> pipes overlap ----
    if (it) {
      const bf16* vs = Vs + ((((it - 1) % 3) * 2) + half) * 4096;
#pragma unroll
      for (int u = 0; u < 3; ++u) lacc[u] = mfma16(ones, pf_prev[u], lacc[u]);
#pragma unroll
      for (int dd = 0; dd < 8; ++dd) {
        bf16x8 vf = *(const bf16x8*)&vs[(dd * 16 + lq) * 32 + ((quad ^ sw) * 8)];
#pragma unroll
        for (int u = 0; u < 3; ++u) o[u][dd] = mfma16(vf, pf_prev[u], o[u][dd]);
      }
    }
    __builtin_amdgcn_s_setprio(0);

    // ---- softmax(it): p = exp2(s); C-layout -> B-frag transpose in-register ----
#pragma unroll
    for (int u = 0; u < 3; ++u) {
      unsigned A0 = pk2(EXP2F(sf[u][0][0]), EXP2F(sf[u][0][1]));
      unsigned A1 = pk2(EXP2F(sf[u][0][2]), EXP2F(sf[u][0][3]));
      unsigned B0 = pk2(EXP2F(sf[u][1][0]), EXP2F(sf[u][1][1]));
      unsigned B1 = pk2(EXP2F(sf[u][1][2]), EXP2F(sf[u][1][3]));
      perm32swap(A0, B0);
      perm16swap(A0, B0);  // A0 = w0 (t=8q+0,1), B0 = w2 (t=8q+4,5)
      perm32swap(A1, B1);
      perm16swap(A1, B1);  // A1 = w1 (t=8q+2,3), B1 = w3 (t=8q+6,7)
      union { unsigned d[4]; bf16x8 v; } pu;
      pu.d[0] = A0; pu.d[1] = A1; pu.d[2] = B0; pu.d[3] = B1;
      pf_prev[u] = pu.v;
    }
  }

  // ---- drain the pipeline: PV(63), V tile 63 lives in slot 63%3 = 0 ----
  {
    const bf16* vs = Vs + (0 * 2 + half) * 4096;
#pragma unroll
    for (int u = 0; u < 3; ++u) lacc[u] = mfma16(ones, pf_prev[u], lacc[u]);
#pragma unroll
    for (int dd = 0; dd < 8; ++dd) {
      bf16x8 vf = *(const bf16x8*)&vs[(dd * 16 + lq) * 32 + ((quad ^ sw) * 8)];
#pragma unroll
      for (int u = 0; u < 3; ++u) o[u][dd] = mfma16(vf, pf_prev[u], o[u][dd]);
    }
  }

  // ---- combine halves in LDS (overlay on Ks/Vs region), then store ----
  __syncthreads();  // all waves done reading K/V
  floatx4* oscr = (floatx4*)smem;           // [pair_slot(0..5)][dd][lane]
  float* lscr = (float*)(smem + 49152);     // [pair_slot][lane]
  if (half == 1) {
#pragma unroll
    for (int u = 0; u < 3; ++u) {
#pragma unroll
      for (int dd = 0; dd < 8; ++dd)
        oscr[((wp * 3 + u) * 8 + dd) * 64 + lane] = o[u][dd];
      lscr[(wp * 3 + u) * 64 + lane] = lacc[u][0];
    }
  }
  __syncthreads();
  if (half == 0) {
    const size_t row = (size_t)b * S + q0 + wp * 16 + lq;
#pragma unroll
    for (int u = 0; u < 3; ++u) {
      float l = lacc[u][0] + lscr[(wp * 3 + u) * 64 + lane];
      float rinv = 1.0f / l;
#pragma unroll
      for (int dd = 0; dd < 8; ++dd) {
        floatx4 oc = o[u][dd] + oscr[((wp * 3 + u) * 8 + dd) * 64 + lane];
        uint2 st;
        st.x = pk2(oc[0] * rinv, oc[1] * rinv);
        st.y = pk2(oc[2] * rinv, oc[3] * rinv);
        int col = (g * REP + u) * HD + dd * 16 + quad * 4;
        *(uint2*)&O[row * (H * HD) + col] = st;
      }
    }
  }
}

// ---------------- launch ----------------
static inline size_t al256(size_t x) { return (x + 255) & ~size_t(255); }

extern "C" void kernel_launch(void* const* d_in, const int* in_sizes, int n_in,
                              void* d_out, int out_size, void* d_ws, size_t ws_size,
                              hipStream_t stream) {
  const float* x  = (const float*)d_in[0];
  const float* wq = (const float*)d_in[1];
  const float* wk = (const float*)d_in[2];
  const float* wv = (const float*)d_in[3];
  const float* wo = (const float*)d_in[4];
  float* out = (float*)d_out;

  char* w = (char*)d_ws;
  size_t off = 0;
  auto carve = [&](size_t elems) {
    bf16* p = (bf16*)(w + off);
    off = al256(off + elems * sizeof(bf16));
    return p;
  };
  bf16* wqkvb = carve((size_t)NQKV * D);  // wq(768) | wk(256) | wv(256) rows
  bf16* wob   = carve((size_t)D * (H * HD));
  bf16* QKVb  = carve((size_t)M_ROWS * NQKV);
  bf16* Vtb   = carve((size_t)M_ROWS * (HK * HD));
  bf16* Ab    = carve((size_t)M_ROWS * (H * HD));

  // (1/sqrt(128)) * log2(e), folded into wq: scores come out in log2 domain
  const float qscale = 0.1275174465f;

  cvt_w<<<(int)(W_WO / 1024), 256, 0, stream>>>(wq, wk, wv, wo, wqkvb, wob, qscale);

  // fused QKV projection: cvt(x)[8192,768] x [1280,768]^T, single 640-block launch;
  // Q/K -> packed C stores, V -> Vt transposed (QKVb V-cols never read)
  gemm_qkv<<<dim3(M_ROWS / 128, NQKV / 128), 256, 0, stream>>>(
      x, wqkvb, QKVb, Vtb, M_ROWS, NQKV, D);

  flash_attn<<<512, 256, 0, stream>>>(QKVb, Vtb, Ab);

  // out projection: 128x64 tiles -> 768 blocks (exactly 3/CU x 256 CUs, 12 waves/CU)
  gemm_out<<<dim3(M_ROWS / 128, D / 64), 256, 0, stream>>>(
      Ab, wob, out, M_ROWS, D, H * HD);
}

// Round 9
// 250.598 us; speedup vs baseline: 1.4378x; 1.4378x over previous
//
#include <hip/hip_runtime.h>
#include <hip/hip_bf16.h>
#include <type_traits>

using bf16 = __hip_bfloat16;
typedef __attribute__((ext_vector_type(8))) short bf16x8;   // 8 bf16 (4 VGPRs) — MFMA A/B frag
typedef __attribute__((ext_vector_type(4))) float floatx4;  // MFMA C/D frag

static constexpr int Bb = 2, S = 4096, D = 768, H = 6, HK = 2, HD = 128, REP = 3;
static constexpr int M_ROWS = Bb * S;   // 8192
static constexpr int NQKV = 1280;       // fused projection width: 768 Q + 256 K + 256 V

__device__ __forceinline__ floatx4 mfma16(bf16x8 a, bf16x8 b, floatx4 c) {
  return __builtin_amdgcn_mfma_f32_16x16x32_bf16(a, b, c, 0, 0, 0);
}

// async global->LDS, 16B/lane; LDS dest = wave-uniform base + lane*16
__device__ __forceinline__ void gld_lds16(const bf16* g, bf16* l) {
  __builtin_amdgcn_global_load_lds(
      (const __attribute__((address_space(1))) unsigned int*)g,
      (__attribute__((address_space(3))) unsigned int*)l, 16, 0, 0);
}

#if defined(__has_builtin)
#if __has_builtin(__builtin_amdgcn_exp2f)
#define EXP2F(x) __builtin_amdgcn_exp2f(x)
#endif
#endif
#ifndef EXP2F
#define EXP2F(x) exp2f(x)
#endif

// pack two fp32 -> 2x bf16 (round-half-up): bias + one v_perm_b32
__device__ __forceinline__ unsigned pk2(float a, float b) {
  unsigned ua = __builtin_bit_cast(unsigned, a) + 0x8000u;
  unsigned ub = __builtin_bit_cast(unsigned, b) + 0x8000u;
#if defined(__has_builtin) && __has_builtin(__builtin_amdgcn_perm)
  return __builtin_amdgcn_perm(ub, ua, 0x07060302);  // {ub.hi16, ua.hi16}
#else
  return (ua >> 16) | (ub & 0xffff0000u);
#endif
}

// gfx950 cross-lane half-swaps (register-only, VALU pipe — no LDS, no waitcnt):
// perm32swap(a,b): a' = [a.q0,a.q1,b.q0,b.q1], b' = [a.q2,a.q3,b.q2,b.q3]   (by 16-lane quads)
// perm16swap(a,b): a' = [a.q0,b.q0,a.q2,b.q2], b' = [a.q1,b.q1,a.q3,b.q3]
__device__ __forceinline__ void perm32swap(unsigned& a, unsigned& b) {
  asm volatile("v_permlane32_swap_b32 %0, %1" : "+v"(a), "+v"(b));
}
__device__ __forceinline__ void perm16swap(unsigned& a, unsigned& b) {
  asm volatile("v_permlane16_swap_b32 %0, %1" : "+v"(a), "+v"(b));
}

// ---------------- fp32 -> bf16 convert, WEIGHTS ONLY ----------------
// x conversion fused into gemm_qkv A-staging; this kernel only converts the
// 1.57M weight elements (~2us) instead of 7.9M.
static constexpr size_t W_WQ = (size_t)H * HD * D;          // 589824
static constexpr size_t W_WK = W_WQ + (size_t)HK * HD * D;  // 786432
static constexpr size_t W_WV = W_WK + (size_t)HK * HD * D;  // 983040
static constexpr size_t W_WO = W_WV + (size_t)D * H * HD;   // 1572864

__global__ __launch_bounds__(256) void cvt_w(const float* __restrict__ wq,
                                             const float* __restrict__ wk,
                                             const float* __restrict__ wv,
                                             const float* __restrict__ wo,
                                             bf16* __restrict__ wqkvb,
                                             bf16* __restrict__ wob, float qscale) {
  size_t i = ((size_t)blockIdx.x * 256 + threadIdx.x) * 4;
  const float* src;
  bf16* dst;
  float s = 1.f;
  size_t off;
  if (i < W_WQ)       { src = wq; dst = wqkvb;              off = i; s = qscale; }
  else if (i < W_WK)  { src = wk; dst = wqkvb + 589824;     off = i - W_WQ; }
  else if (i < W_WV)  { src = wv; dst = wqkvb + 786432;     off = i - W_WK; }
  else                { src = wo; dst = wob;                off = i - W_WV; }
  float4 v = *(const float4*)(src + off);
  uint2 st;
  st.x = pk2(v.x * s, v.y * s);
  st.y = pk2(v.z * s, v.w * s);
  *(uint2*)(dst + off) = st;
}

// ---------------- fused QKV projection GEMM: f32-A reg-staging + dual epilogue ------------
// C[M,N] = cvt(X)[M,K] @ W[N,K]^T. 128x128 tile, BK=64, single 640-block launch.
// R8 POST-MORTEM: acc SPILLED to scratch (VGPR=84 < acc's 64+pf's 32; 351MB scratch writes,
// kernel became HBM-bound at 175us). Cause: qk-branch INSIDE the K-loop + pf[8] live across
// the whole compute region (prologue-pipelined prefetch) -> peak pressure > the (256,3) cap.
// R9 fix: (1) branch OUTSIDE the loop (two self-contained K-loops, R7's known-good shape);
// (2) no cross-iteration pf: per K-step, issue 8 A-float4 loads, then W gld_lds (independent,
// same vmcnt FIFO -> overlapped), then pack+ds_write (waits A only), then barrier (drains W).
// Exposed A-latency hides under the W-DMA drain the barrier pays anyway. pf dies in the
// staging region -> peak ~148 regs < 168 cap.
// A staging layout: thread (ar=tid>>1, half=tid&1) owns row ar, chunks half*4..+3; chunk c
// stored at position c^(ar&7) — identical to the layout gld_lds staging produced.
// Dual epilogue (R7): n0<1024 Q/K swapped-MFMA + packed uint2 stores; n0>=1024 V ->
// verified LDS-transpose -> Vt[b][g][d][t]. Values bit-identical to the reference chain.
// Dispatch note: bid = m + 64*n -> same-m blocks land on the SAME XCD -> x f32 panel
// re-reads (10 n-tiles) are L2-local. No XCD swizzle.
__global__ __launch_bounds__(256, 3) void gemm_qkv(const float* __restrict__ X,
                                                   const bf16* __restrict__ W,
                                                   bf16* __restrict__ C,
                                                   bf16* __restrict__ Vt,
                                                   int M, int N, int K) {
  const int tid = threadIdx.x;
  const int wave = tid >> 6, lane = tid & 63;
  const int quad = lane >> 4, lq = lane & 15;
  const int m0 = blockIdx.x * 128, n0 = blockIdx.y * 128;
  const int wm = (wave & 1) * 64, wn = (wave >> 1) * 64;

  __shared__ __align__(16) bf16 As[128 * 64];  // 16 KB
  __shared__ __align__(16) bf16 Ws[128 * 64];  // 16 KB

  floatx4 acc[4][4] = {};

  const int srow = lane >> 3, sc = lane & 7;   // W staging: 8 rows x 8 chunks per issue
  const int ar = tid >> 1, cb = (tid & 1) * 4; // A staging: row + chunk-quad ownership

  const float* Ag = X + (size_t)(m0 + ar) * K + (tid & 1) * 32;
  bf16* Ad = &As[ar * 64];
  const int akey = ar & 7;

  // A loads -> W DMA -> pack+ds_write (vmcnt waits A; W drains at the barrier)
  auto stageAW = [&](int k0) {
    float4 pf[8];
#pragma unroll
    for (int j = 0; j < 8; ++j) pf[j] = *(const float4*)(Ag + k0 + j * 4);
#pragma unroll
    for (int i = 0; i < 4; ++i) {
      int ig = wave * 4 + i;               // 0..15
      int r = ig * 8 + srow;               // 0..127
      int c = sc ^ (r & 7);
      gld_lds16(&W[(size_t)(n0 + r) * K + k0 + c * 8], &Ws[ig * 512]);
    }
#pragma unroll
    for (int t = 0; t < 4; ++t) {
      int c = cb + t;
      uint4 st;
      st.x = pk2(pf[2 * t].x, pf[2 * t].y);
      st.y = pk2(pf[2 * t].z, pf[2 * t].w);
      st.z = pk2(pf[2 * t + 1].x, pf[2 * t + 1].y);
      st.w = pk2(pf[2 * t + 1].z, pf[2 * t + 1].w);
      *(uint4*)(Ad + ((c ^ akey) * 8)) = st;
    }
  };

  if (n0 < 1024) {
    // ---------------- Q/K path: swapped operands, packed epilogue ----------------
    for (int k0 = 0; k0 < K; k0 += 64) {
      stageAW(k0);
      __syncthreads();
#pragma unroll
      for (int kh = 0; kh < 2; ++kh) {
        bf16x8 af[4], wf[4];
#pragma unroll
        for (int i = 0; i < 4; ++i) {
          int ra = wm + i * 16 + lq, rw = wn + i * 16 + lq;
          af[i] = *(const bf16x8*)&As[ra * 64 + (((kh * 4 + quad) ^ (ra & 7)) * 8)];
          wf[i] = *(const bf16x8*)&Ws[rw * 64 + (((kh * 4 + quad) ^ (rw & 7)) * 8)];
        }
#pragma unroll
        for (int i = 0; i < 4; ++i)
#pragma unroll
          for (int j = 0; j < 4; ++j) acc[i][j] = mfma16(wf[j], af[i], acc[i][j]);  // swapped
      }
      __syncthreads();
    }
    // packed epilogue: lane(quad,lq) -> row m0+wm+i*16+lq, cols n0+wn+j*16+quad*4 .. +3
#pragma unroll
    for (int i = 0; i < 4; ++i)
#pragma unroll
      for (int j = 0; j < 4; ++j) {
        uint2 st;
        st.x = pk2(acc[i][j][0], acc[i][j][1]);
        st.y = pk2(acc[i][j][2], acc[i][j][3]);
        int row = m0 + wm + i * 16 + lq;
        int col = n0 + wn + j * 16 + quad * 4;
        *(uint2*)&C[(size_t)row * N + col] = st;
      }
    return;
  }

  // ---------------- V path: original order, Vt-transpose epilogue ----------------
  for (int k0 = 0; k0 < K; k0 += 64) {
    stageAW(k0);
    __syncthreads();
#pragma unroll
    for (int kh = 0; kh < 2; ++kh) {
      bf16x8 af[4], wf[4];
#pragma unroll
      for (int i = 0; i < 4; ++i) {
        int ra = wm + i * 16 + lq, rw = wn + i * 16 + lq;
        af[i] = *(const bf16x8*)&As[ra * 64 + (((kh * 4 + quad) ^ (ra & 7)) * 8)];
        wf[i] = *(const bf16x8*)&Ws[rw * 64 + (((kh * 4 + quad) ^ (rw & 7)) * 8)];
      }
#pragma unroll
      for (int i = 0; i < 4; ++i)
#pragma unroll
        for (int j = 0; j < 4; ++j) acc[i][j] = mfma16(af[i], wf[j], acc[i][j]);
    }
    __syncthreads();
  }

  // col-XOR-swizzled LDS transpose, then coalesced b128 stores to Vt[b][g][d][t]
  bf16* tb = (wave < 2 ? As : Ws) + (wave & 1) * 4096;
  char* tc = (char*)tb;
#pragma unroll
  for (int i = 0; i < 4; ++i)
#pragma unroll
    for (int j = 0; j < 4; ++j) {
      uint2 st;
      st.x = pk2(acc[i][j][0], acc[i][j][1]);
      st.y = pk2(acc[i][j][2], acc[i][j][3]);
      int col = j * 16 + lq;
      int cc = (i * 2 + (quad >> 1)) ^ (col & 7);
      *(uint2*)(tc + col * 128 + cc * 16 + (quad & 1) * 8) = st;
    }
  const int b = m0 >> 12;  // uniform per block (128-row tiles never cross S)
  const int dd_off = lane >> 3, schunk = lane & 7;
  const int sbase = (m0 & 4095) + wm + schunk * 8;
#pragma unroll
  for (int e = 0; e < 8; ++e) {
    int cl = e * 8 + dd_off;                      // local col 0..63
    int col = (n0 - 1024) + wn + cl;              // 0..255
    int gg = col >> 7, dd = col & 127;
    bf16x8 vv = *(const bf16x8*)(tc + cl * 128 + ((schunk ^ (cl & 7)) * 16));
    *(bf16x8*)&Vt[((size_t)(b * HK + gg) * HD + dd) * S + sbase] = vv;
  }
}

// ---------------- out-projection GEMM: 128x64 tile, swapped operands + float4 stores ----------------
// 128x64 tiles -> 768 blocks = exactly 3/CU x 256 CUs, 12 waves/CU, single full round.
// Swapped-operand MFMA -> lane holds 4 row-contiguous f32 -> one 16B store per tile.
__global__ __launch_bounds__(256, 3) void gemm_out(const bf16* __restrict__ A,
                                                   const bf16* __restrict__ W,
                                                   float* __restrict__ C,
                                                   int M, int N, int K) {
  const int tid = threadIdx.x;
  const int wave = tid >> 6, lane = tid & 63;
  const int quad = lane >> 4, lq = lane & 15;
  const int m0 = blockIdx.x * 128, n0 = blockIdx.y * 64;
  const int wm = (wave & 1) * 64, wn = (wave >> 1) * 32;

  __shared__ __align__(16) bf16 As[128 * 64];  // 16 KB
  __shared__ __align__(16) bf16 Ws[64 * 64];   // 8 KB

  floatx4 acc[4][2] = {};

  const int srow = lane >> 3, sc = lane & 7;  // staging: 8 rows x 8 chunks per issue

  for (int k0 = 0; k0 < K; k0 += 64) {
#pragma unroll
    for (int i = 0; i < 4; ++i) {
      int ig = wave * 4 + i;               // 0..15
      int r = ig * 8 + srow;               // 0..127
      int c = sc ^ (r & 7);
      gld_lds16(&A[(size_t)(m0 + r) * K + k0 + c * 8], &As[ig * 512]);
    }
#pragma unroll
    for (int i = 0; i < 2; ++i) {
      int ig = wave * 2 + i;               // 0..7
      int r = ig * 8 + srow;               // 0..63
      int c = sc ^ (r & 7);
      gld_lds16(&W[(size_t)(n0 + r) * K + k0 + c * 8], &Ws[ig * 512]);
    }
    __syncthreads();
#pragma unroll
    for (int kh = 0; kh < 2; ++kh) {
      bf16x8 af[4], wf[2];
#pragma unroll
      for (int i = 0; i < 4; ++i) {
        int ra = wm + i * 16 + lq;
        af[i] = *(const bf16x8*)&As[ra * 64 + (((kh * 4 + quad) ^ (ra & 7)) * 8)];
      }
#pragma unroll
      for (int j = 0; j < 2; ++j) {
        int rw = wn + j * 16 + lq;
        wf[j] = *(const bf16x8*)&Ws[rw * 64 + (((kh * 4 + quad) ^ (rw & 7)) * 8)];
      }
#pragma unroll
      for (int i = 0; i < 4; ++i)
#pragma unroll
        for (int j = 0; j < 2; ++j) acc[i][j] = mfma16(wf[j], af[i], acc[i][j]);  // swapped
    }
    __syncthreads();
  }
#pragma unroll
  for (int i = 0; i < 4; ++i)
#pragma unroll
    for (int j = 0; j < 2; ++j) {
      int row = m0 + wm + i * 16 + lq;
      int col = n0 + wn + j * 16 + quad * 4;
      *(floatx4*)&C[(size_t)row * N + col] = acc[i][j];
    }
}

// ---------------- Flash attention: S-transposed, no-max softmax, intra-block split-K ----------------
// R3 BEST-KNOWN-GOOD (~110-115 us, ~920 TF effective): LDS DMA K dbuf + V 3-buf, deferred-PV,
// in-register P^T transpose, 1 barrier/iter, 4-wave blocks, 2 blocks/CU (8 waves/CU).
// Bracketing of this plateau (keep for posterity):
//   R0 setprio: ~0.  R1 in-reg transpose: +8% (conflicts 3.15M->0).  R2/R3 deferred-PV: ~0
//   (both MFMA pools share one matrix pipe).  R4 2-wave blocks: -35% (4 waves/CU: perf is
//   ~linear in waves/CU; 2048 waves is the structural max for this decomposition).
//   R5 V-from-global PV: -33% (per-wave vmcnt stalls at 2 waves/SIMD — same mode as r8;
//   LDS DMA is the only latency structure that works at this occupancy).
__global__ __launch_bounds__(256, 2) void flash_attn(const bf16* __restrict__ QKV,
                                                     const bf16* __restrict__ Vt,
                                                     bf16* __restrict__ O) {
  const int bid = blockIdx.x;
  const int bg = (bid & 7) >> 1;                 // 0..3 -> (b,g), XCD-clustered
  const int b = bg >> 1, g = bg & 1;
  const int qt = ((bid >> 3) << 1) | (bid & 1);  // 0..127
  const int q0 = qt * 32;

  const int tid = threadIdx.x;
  const int w = tid >> 6, lane = tid & 63;
  const int half = w >> 1, wp = w & 1;           // KV-half, index within pair
  const int quad = lane >> 4, lq = lane & 15;

  __shared__ __align__(16) char smem[81920];
  bf16* Ks = (bf16*)smem;            // [kbuf 0..1][half][32*128], chunk c at c^(trow&15)
  bf16* Vs = (bf16*)(smem + 32768);  // [vbuf 0..2][half][128*32], chunk c at c^((drow>>1)&3)

  const bf16* Kgh = QKV + (size_t)b * S * NQKV + H * HD + g * HD + (size_t)half * 2048 * NQKV;
  const bf16* Vgh = Vt + (size_t)(b * HK + g) * HD * S + half * 2048;

  auto stage = [&](int t0, int kbuf, int vbuf) {
    bf16* kd = Ks + (kbuf * 2 + half) * 4096;
    bf16* vd = Vs + (vbuf * 2 + half) * 4096;
#pragma unroll
    for (int i = 0; i < 4; ++i) {
      int ig = wp * 4 + i;                 // 0..7
      int tl = ig * 4 + (lane >> 4);       // 0..31
      int c = (lane & 15) ^ (tl & 15);
      gld_lds16(Kgh + (size_t)(t0 + tl) * NQKV + c * 8, kd + ig * 512);
    }
#pragma unroll
    for (int i = 0; i < 4; ++i) {
      int ig = wp * 4 + i;
      int dl = ig * 16 + (lane >> 2);      // 0..127
      int c = (lane & 3) ^ ((dl >> 1) & 3);
      gld_lds16(Vgh + (size_t)dl * S + t0 + c * 8, vd + ig * 512);
    }
  };

  stage(0, 0, 0);  // prologue: tile 0 -> kbuf 0, vbuf 0

  // Q fragments: B-operand layout (n=lane&15 -> q-row, k=quad*8+j -> d)
  const bf16* Qg = QKV + ((size_t)b * S + q0 + wp * 16 + lq) * NQKV + g * REP * HD;
  bf16x8 qf[3][4];
#pragma unroll
  for (int u = 0; u < 3; ++u)
#pragma unroll
    for (int kk = 0; kk < 4; ++kk)
      qf[u][kk] = *(const bf16x8*)(Qg + u * HD + kk * 32 + quad * 8);

  bf16x8 ones;
#pragma unroll
  for (int j = 0; j < 8; ++j) ones[j] = (short)0x3F80;  // bf16 1.0

  floatx4 o[3][8] = {};
  floatx4 lacc[3] = {};           // denominator via ones-MFMA (all regs = row-sum)
  bf16x8 pf_prev[3];              // P^T B-frags of tile it-1 (deferred-PV state)
  const int sw = (lq >> 1) & 3;   // swizzle key (V layout)

#pragma unroll 2
  for (int it = 0; it < 64; ++it) {
    const int kcur = it & 1;
    __syncthreads();  // K/V[it] staged; V[it-1] still intact (3-buf)
    if (it + 1 < 64) stage((it + 1) * 32, kcur ^ 1, (it + 1) % 3);

    const bf16* ks = Ks + (kcur * 2 + half) * 4096;

    // ---- S^T(it) = K Q^T : kf read once, reused by 3 heads ----
    floatx4 sf[3][2] = {};
    __builtin_amdgcn_s_setprio(1);
#pragma unroll
    for (int tt = 0; tt < 2; ++tt)
#pragma unroll
      for (int kk = 0; kk < 4; ++kk) {
        int c = (kk * 4 + quad) ^ lq;  // t row = tt*16+lq -> key lq
        bf16x8 kf = *(const bf16x8*)&ks[(tt * 16 + lq) * 128 + c * 8];
#pragma unroll
        for (int u = 0; u < 3; ++u) sf[u][tt] = mfma16(kf, qf[u][kk], sf[u][tt]);
      }

    // ---- deferred PV(it-1): independent of QK^T(it) above -> pipes overlap ----
    if (it) {
      const bf16* vs = Vs + ((((it - 1) % 3) * 2) + half) * 4096;
#pragma unroll
      for (int u = 0; u < 3; ++u) lacc[u] = mfma16(ones, pf_prev[u], lacc[u]);
#pragma unroll
      for (int dd = 0; dd < 8; ++dd) {
        bf16x8 vf = *(const bf16x8*)&vs[(dd * 16 + lq) * 32 + ((quad ^ sw) * 8)];
#pragma unroll
        for (int u = 0; u < 3; ++u) o[u][dd] = mfma16(vf, pf_prev[u], o[u][dd]);
      }
    }
    __builtin_amdgcn_s_setprio(0);

    // ---- softmax(it): p = exp2(s); C-layout -> B-frag transpose in-register ----
#pragma unroll
    for (int u = 0; u < 3; ++u) {
      unsigned A0 = pk2(EXP2F(sf[u][0][0]), EXP2F(sf[u][0][1]));
      unsigned A1 = pk2(EXP2F(sf[u][0][2]), EXP2F(sf[u][0][3]));
      unsigned B0 = pk2(EXP2F(sf[u][1][0]), EXP2F(sf[u][1][1]));
      unsigned B1 = pk2(EXP2F(sf[u][1][2]), EXP2F(sf[u][1][3]));
      perm32swap(A0, B0);
      perm16swap(A0, B0);  // A0 = w0 (t=8q+0,1), B0 = w2 (t=8q+4,5)
      perm32swap(A1, B1);
      perm16swap(A1, B1);  // A1 = w1 (t=8q+2,3), B1 = w3 (t=8q+6,7)
      union { unsigned d[4]; bf16x8 v; } pu;
      pu.d[0] = A0; pu.d[1] = A1; pu.d[2] = B0; pu.d[3] = B1;
      pf_prev[u] = pu.v;
    }
  }

  // ---- drain the pipeline: PV(63), V tile 63 lives in slot 63%3 = 0 ----
  {
    const bf16* vs = Vs + (0 * 2 + half) * 4096;
#pragma unroll
    for (int u = 0; u < 3; ++u) lacc[u] = mfma16(ones, pf_prev[u], lacc[u]);
#pragma unroll
    for (int dd = 0; dd < 8; ++dd) {
      bf16x8 vf = *(const bf16x8*)&vs[(dd * 16 + lq) * 32 + ((quad ^ sw) * 8)];
#pragma unroll
      for (int u = 0; u < 3; ++u) o[u][dd] = mfma16(vf, pf_prev[u], o[u][dd]);
    }
  }

  // ---- combine halves in LDS (overlay on Ks/Vs region), then store ----
  __syncthreads();  // all waves done reading K/V
  floatx4* oscr = (floatx4*)smem;           // [pair_slot(0..5)][dd][lane]
  float* lscr = (float*)(smem + 49152);     // [pair_slot][lane]
  if (half == 1) {
#pragma unroll
    for (int u = 0; u < 3; ++u) {
#pragma unroll
      for (int dd = 0; dd < 8; ++dd)
        oscr[((wp * 3 + u) * 8 + dd) * 64 + lane] = o[u][dd];
      lscr[(wp * 3 + u) * 64 + lane] = lacc[u][0];
    }
  }
  __syncthreads();
  if (half == 0) {
    const size_t row = (size_t)b * S + q0 + wp * 16 + lq;
#pragma unroll
    for (int u = 0; u < 3; ++u) {
      float l = lacc[u][0] + lscr[(wp * 3 + u) * 64 + lane];
      float rinv = 1.0f / l;
#pragma unroll
      for (int dd = 0; dd < 8; ++dd) {
        floatx4 oc = o[u][dd] + oscr[((wp * 3 + u) * 8 + dd) * 64 + lane];
        uint2 st;
        st.x = pk2(oc[0] * rinv, oc[1] * rinv);
        st.y = pk2(oc[2] * rinv, oc[3] * rinv);
        int col = (g * REP + u) * HD + dd * 16 + quad * 4;
        *(uint2*)&O[row * (H * HD) + col] = st;
      }
    }
  }
}

// ---------------- launch ----------------
static inline size_t al256(size_t x) { return (x + 255) & ~size_t(255); }

extern "C" void kernel_launch(void* const* d_in, const int* in_sizes, int n_in,
                              void* d_out, int out_size, void* d_ws, size_t ws_size,
                              hipStream_t stream) {
  const float* x  = (const float*)d_in[0];
  const float* wq = (const float*)d_in[1];
  const float* wk = (const float*)d_in[2];
  const float* wv = (const float*)d_in[3];
  const float* wo = (const float*)d_in[4];
  float* out = (float*)d_out;

  char* w = (char*)d_ws;
  size_t off = 0;
  auto carve = [&](size_t elems) {
    bf16* p = (bf16*)(w + off);
    off = al256(off + elems * sizeof(bf16));
    return p;
  };
  bf16* wqkvb = carve((size_t)NQKV * D);  // wq(768) | wk(256) | wv(256) rows
  bf16* wob   = carve((size_t)D * (H * HD));
  bf16* QKVb  = carve((size_t)M_ROWS * NQKV);
  bf16* Vtb   = carve((size_t)M_ROWS * (HK * HD));
  bf16* Ab    = carve((size_t)M_ROWS * (H * HD));

  // (1/sqrt(128)) * log2(e), folded into wq: scores come out in log2 domain
  const float qscale = 0.1275174465f;

  cvt_w<<<(int)(W_WO / 1024), 256, 0, stream>>>(wq, wk, wv, wo, wqkvb, wob, qscale);

  // fused QKV projection: cvt(x)[8192,768] x [1280,768]^T, single 640-block launch;
  // Q/K -> packed C stores, V -> Vt transposed (QKVb V-cols never read)
  gemm_qkv<<<dim3(M_ROWS / 128, NQKV / 128), 256, 0, stream>>>(
      x, wqkvb, QKVb, Vtb, M_ROWS, NQKV, D);

  flash_attn<<<512, 256, 0, stream>>>(QKVb, Vtb, Ab);

  // out projection: 128x64 tiles -> 768 blocks (exactly 3/CU x 256 CUs, 12 waves/CU)
  gemm_out<<<dim3(M_ROWS / 128, D / 64), 256, 0, stream>>>(
      Ab, wob, out, M_ROWS, D, H * HD);
}

// Round 10
// 223.319 us; speedup vs baseline: 1.6134x; 1.1222x over previous
//
#include <hip/hip_runtime.h>
#include <hip/hip_bf16.h>
#include <type_traits>

using bf16 = __hip_bfloat16;
typedef __attribute__((ext_vector_type(8))) short bf16x8;   // 8 bf16 (4 VGPRs) — MFMA A/B frag
typedef __attribute__((ext_vector_type(4))) float floatx4;  // MFMA C/D frag

static constexpr int Bb = 2, S = 4096, D = 768, H = 6, HK = 2, HD = 128, REP = 3;
static constexpr int M_ROWS = Bb * S;   // 8192
static constexpr int NQKV = 1280;       // fused projection width: 768 Q + 256 K + 256 V

__device__ __forceinline__ floatx4 mfma16(bf16x8 a, bf16x8 b, floatx4 c) {
  return __builtin_amdgcn_mfma_f32_16x16x32_bf16(a, b, c, 0, 0, 0);
}

// async global->LDS, 16B/lane; LDS dest = wave-uniform base + lane*16
__device__ __forceinline__ void gld_lds16(const bf16* g, bf16* l) {
  __builtin_amdgcn_global_load_lds(
      (const __attribute__((address_space(1))) unsigned int*)g,
      (__attribute__((address_space(3))) unsigned int*)l, 16, 0, 0);
}

#if defined(__has_builtin)
#if __has_builtin(__builtin_amdgcn_exp2f)
#define EXP2F(x) __builtin_amdgcn_exp2f(x)
#endif
#endif
#ifndef EXP2F
#define EXP2F(x) exp2f(x)
#endif

// pack two fp32 -> 2x bf16 (round-half-up): bias + one v_perm_b32
__device__ __forceinline__ unsigned pk2(float a, float b) {
  unsigned ua = __builtin_bit_cast(unsigned, a) + 0x8000u;
  unsigned ub = __builtin_bit_cast(unsigned, b) + 0x8000u;
#if defined(__has_builtin) && __has_builtin(__builtin_amdgcn_perm)
  return __builtin_amdgcn_perm(ub, ua, 0x07060302);  // {ub.hi16, ua.hi16}
#else
  return (ua >> 16) | (ub & 0xffff0000u);
#endif
}

// gfx950 cross-lane half-swaps (register-only, VALU pipe — no LDS, no waitcnt):
// perm32swap(a,b): a' = [a.q0,a.q1,b.q0,b.q1], b' = [a.q2,a.q3,b.q2,b.q3]   (by 16-lane quads)
// perm16swap(a,b): a' = [a.q0,b.q0,a.q2,b.q2], b' = [a.q1,b.q1,a.q3,b.q3]
__device__ __forceinline__ void perm32swap(unsigned& a, unsigned& b) {
  asm volatile("v_permlane32_swap_b32 %0, %1" : "+v"(a), "+v"(b));
}
__device__ __forceinline__ void perm16swap(unsigned& a, unsigned& b) {
  asm volatile("v_permlane16_swap_b32 %0, %1" : "+v"(a), "+v"(b));
}

// ---------------- fused fp32 -> bf16 convert for all 5 inputs ----------------
// R8/R9 LESSON: fusing the x-conversion into gemm_qkv A-staging LOSES. R8: acc spilled
// (branch-in-loop + pf live across compute -> VGPR 84, 350MB scratch, 175us). R9 (spill
// fixed, tight liveness): still +28us vs this path — reg-staging (load->vmcnt->pack->
// ds_write) exposes serial VMEM latency that 3 blocks/CU can't hide; fire-and-forget
// global_load_lds DMA is the only staging structure that works at this occupancy
// (same mode as flash R5). The standalone cvt round-trip is the cheaper design.
static constexpr size_t E_X  = (size_t)M_ROWS * D;                 // 6291456
static constexpr size_t E_WQ = E_X + (size_t)H * HD * D;           // +589824
static constexpr size_t E_WK = E_WQ + (size_t)HK * HD * D;         // +196608
static constexpr size_t E_WV = E_WK + (size_t)HK * HD * D;         // +196608
static constexpr size_t E_WO = E_WV + (size_t)D * H * HD;          // +589824 = 7864320

__global__ __launch_bounds__(256) void cvt_all(const float* __restrict__ x,
                                               const float* __restrict__ wq,
                                               const float* __restrict__ wk,
                                               const float* __restrict__ wv,
                                               const float* __restrict__ wo,
                                               bf16* __restrict__ xb,
                                               bf16* __restrict__ wqkvb,
                                               bf16* __restrict__ wob, float qscale) {
  size_t i = ((size_t)blockIdx.x * 256 + threadIdx.x) * 4;
  const float* src;
  bf16* dst;
  float s = 1.f;
  size_t off;
  if (i < E_X)        { src = x;  dst = xb;                 off = i; }
  else if (i < E_WQ)  { src = wq; dst = wqkvb;              off = i - E_X; s = qscale; }
  else if (i < E_WK)  { src = wk; dst = wqkvb + 589824;     off = i - E_WQ; }
  else if (i < E_WV)  { src = wv; dst = wqkvb + 786432;     off = i - E_WK; }
  else                { src = wo; dst = wob;                off = i - E_WV; }
  float4 v = *(const float4*)(src + off);
  uint2 st;
  st.x = pk2(v.x * s, v.y * s);
  st.y = pk2(v.z * s, v.w * s);
  *(uint2*)(dst + off) = st;
}

// ---------------- fused QKV projection GEMM: single 640-block launch, dual epilogue ------------
// C[M,N] = A[M,K] @ W[N,K]^T. 128x128 tile, BK=64, global_load_lds width-16, XOR-swizzled LDS.
// Merged single launch (R6 lesson: splitting cost 2.0/0.5 blocks/CU occupancy + extra launch
// + A re-read = +8us; combined 640 blocks = 2.5/CU is better).
// Dual epilogue, block-uniform branch on n0 (OUTSIDE the K-loop — R8 lesson: in-loop branch
// merges live ranges and spills acc):
//   n0 < 1024 (Q/K): K-loop uses SWAPPED mfma16(wf, af) -> transposed fragment: lane(quad,lq)
//     holds row m=lq, cols n=quad*4+r (4 row-contiguous) -> one packed uint2 store per tile.
//     Bit-identical values (same k-order).
//   n0 >= 1024 (V): original operand order feeding the verified col-XOR-swizzled LDS
//     transpose -> coalesced b128 stores to Vt[b][g][d][t]. No C write (V-cols never read).
// Dispatch note: bid = m + 64*n -> same-m blocks land on the SAME XCD (64 = 0 mod 8) ->
// A panels are L2-local. No XCD swizzle.
__global__ __launch_bounds__(256, 3) void gemm_qkv(const bf16* __restrict__ A,
                                                   const bf16* __restrict__ W,
                                                   bf16* __restrict__ C,
                                                   bf16* __restrict__ Vt,
                                                   int M, int N, int K) {
  const int tid = threadIdx.x;
  const int wave = tid >> 6, lane = tid & 63;
  const int quad = lane >> 4, lq = lane & 15;
  const int m0 = blockIdx.x * 128, n0 = blockIdx.y * 128;
  const int wm = (wave & 1) * 64, wn = (wave >> 1) * 64;

  __shared__ __align__(16) bf16 As[128 * 64];  // 16 KB
  __shared__ __align__(16) bf16 Ws[128 * 64];  // 16 KB

  floatx4 acc[4][4] = {};

  const int srow = lane >> 3, sc = lane & 7;  // staging: 8 rows x 8 chunks per issue

  if (n0 < 1024) {
    // ---------------- Q/K path: swapped operands, packed epilogue ----------------
    for (int k0 = 0; k0 < K; k0 += 64) {
#pragma unroll
      for (int i = 0; i < 4; ++i) {
        int ig = wave * 4 + i;               // 0..15
        int r = ig * 8 + srow;               // 0..127
        int c = sc ^ (r & 7);
        gld_lds16(&A[(size_t)(m0 + r) * K + k0 + c * 8], &As[ig * 512]);
        gld_lds16(&W[(size_t)(n0 + r) * K + k0 + c * 8], &Ws[ig * 512]);
      }
      __syncthreads();
#pragma unroll
      for (int kh = 0; kh < 2; ++kh) {
        bf16x8 af[4], wf[4];
#pragma unroll
        for (int i = 0; i < 4; ++i) {
          int ra = wm + i * 16 + lq, rw = wn + i * 16 + lq;
          af[i] = *(const bf16x8*)&As[ra * 64 + (((kh * 4 + quad) ^ (ra & 7)) * 8)];
          wf[i] = *(const bf16x8*)&Ws[rw * 64 + (((kh * 4 + quad) ^ (rw & 7)) * 8)];
        }
#pragma unroll
        for (int i = 0; i < 4; ++i)
#pragma unroll
          for (int j = 0; j < 4; ++j) acc[i][j] = mfma16(wf[j], af[i], acc[i][j]);  // swapped
      }
      __syncthreads();
    }
    // packed epilogue: lane(quad,lq) -> row m0+wm+i*16+lq, cols n0+wn+j*16+quad*4 .. +3
#pragma unroll
    for (int i = 0; i < 4; ++i)
#pragma unroll
      for (int j = 0; j < 4; ++j) {
        uint2 st;
        st.x = pk2(acc[i][j][0], acc[i][j][1]);
        st.y = pk2(acc[i][j][2], acc[i][j][3]);
        int row = m0 + wm + i * 16 + lq;
        int col = n0 + wn + j * 16 + quad * 4;
        *(uint2*)&C[(size_t)row * N + col] = st;
      }
    return;
  }

  // ---------------- V path: original order, Vt-transpose epilogue ----------------
  for (int k0 = 0; k0 < K; k0 += 64) {
#pragma unroll
    for (int i = 0; i < 4; ++i) {
      int ig = wave * 4 + i;               // 0..15
      int r = ig * 8 + srow;               // 0..127
      int c = sc ^ (r & 7);
      gld_lds16(&A[(size_t)(m0 + r) * K + k0 + c * 8], &As[ig * 512]);
      gld_lds16(&W[(size_t)(n0 + r) * K + k0 + c * 8], &Ws[ig * 512]);
    }
    __syncthreads();
#pragma unroll
    for (int kh = 0; kh < 2; ++kh) {
      bf16x8 af[4], wf[4];
#pragma unroll
      for (int i = 0; i < 4; ++i) {
        int ra = wm + i * 16 + lq, rw = wn + i * 16 + lq;
        af[i] = *(const bf16x8*)&As[ra * 64 + (((kh * 4 + quad) ^ (ra & 7)) * 8)];
        wf[i] = *(const bf16x8*)&Ws[rw * 64 + (((kh * 4 + quad) ^ (rw & 7)) * 8)];
      }
#pragma unroll
      for (int i = 0; i < 4; ++i)
#pragma unroll
        for (int j = 0; j < 4; ++j) acc[i][j] = mfma16(af[i], wf[j], acc[i][j]);
    }
    __syncthreads();
  }

  // col-XOR-swizzled LDS transpose, then coalesced b128 stores to Vt[b][g][d][t]
  bf16* tb = (wave < 2 ? As : Ws) + (wave & 1) * 4096;
  char* tc = (char*)tb;
#pragma unroll
  for (int i = 0; i < 4; ++i)
#pragma unroll
    for (int j = 0; j < 4; ++j) {
      uint2 st;
      st.x = pk2(acc[i][j][0], acc[i][j][1]);
      st.y = pk2(acc[i][j][2], acc[i][j][3]);
      int col = j * 16 + lq;
      int cc = (i * 2 + (quad >> 1)) ^ (col & 7);
      *(uint2*)(tc + col * 128 + cc * 16 + (quad & 1) * 8) = st;
    }
  const int b = m0 >> 12;  // uniform per block (128-row tiles never cross S)
  const int dd_off = lane >> 3, schunk = lane & 7;
  const int sbase = (m0 & 4095) + wm + schunk * 8;
#pragma unroll
  for (int e = 0; e < 8; ++e) {
    int cl = e * 8 + dd_off;                      // local col 0..63
    int col = (n0 - 1024) + wn + cl;              // 0..255
    int gg = col >> 7, dd = col & 127;
    bf16x8 vv = *(const bf16x8*)(tc + cl * 128 + ((schunk ^ (cl & 7)) * 16));
    *(bf16x8*)&Vt[((size_t)(b * HK + gg) * HD + dd) * S + sbase] = vv;
  }
}

// ---------------- out-projection GEMM: 128x64 tile, swapped operands + float4 stores ----------------
// 128x64 tiles -> 768 blocks = exactly 3/CU x 256 CUs, 12 waves/CU, single full round.
// Swapped-operand MFMA -> lane holds 4 row-contiguous f32 -> one 16B store per tile.
__global__ __launch_bounds__(256, 3) void gemm_out(const bf16* __restrict__ A,
                                                   const bf16* __restrict__ W,
                                                   float* __restrict__ C,
                                                   int M, int N, int K) {
  const int tid = threadIdx.x;
  const int wave = tid >> 6, lane = tid & 63;
  const int quad = lane >> 4, lq = lane & 15;
  const int m0 = blockIdx.x * 128, n0 = blockIdx.y * 64;
  const int wm = (wave & 1) * 64, wn = (wave >> 1) * 32;

  __shared__ __align__(16) bf16 As[128 * 64];  // 16 KB
  __shared__ __align__(16) bf16 Ws[64 * 64];   // 8 KB

  floatx4 acc[4][2] = {};

  const int srow = lane >> 3, sc = lane & 7;  // staging: 8 rows x 8 chunks per issue

  for (int k0 = 0; k0 < K; k0 += 64) {
#pragma unroll
    for (int i = 0; i < 4; ++i) {
      int ig = wave * 4 + i;               // 0..15
      int r = ig * 8 + srow;               // 0..127
      int c = sc ^ (r & 7);
      gld_lds16(&A[(size_t)(m0 + r) * K + k0 + c * 8], &As[ig * 512]);
    }
#pragma unroll
    for (int i = 0; i < 2; ++i) {
      int ig = wave * 2 + i;               // 0..7
      int r = ig * 8 + srow;               // 0..63
      int c = sc ^ (r & 7);
      gld_lds16(&W[(size_t)(n0 + r) * K + k0 + c * 8], &Ws[ig * 512]);
    }
    __syncthreads();
#pragma unroll
    for (int kh = 0; kh < 2; ++kh) {
      bf16x8 af[4], wf[2];
#pragma unroll
      for (int i = 0; i < 4; ++i) {
        int ra = wm + i * 16 + lq;
        af[i] = *(const bf16x8*)&As[ra * 64 + (((kh * 4 + quad) ^ (ra & 7)) * 8)];
      }
#pragma unroll
      for (int j = 0; j < 2; ++j) {
        int rw = wn + j * 16 + lq;
        wf[j] = *(const bf16x8*)&Ws[rw * 64 + (((kh * 4 + quad) ^ (rw & 7)) * 8)];
      }
#pragma unroll
      for (int i = 0; i < 4; ++i)
#pragma unroll
        for (int j = 0; j < 2; ++j) acc[i][j] = mfma16(wf[j], af[i], acc[i][j]);  // swapped
    }
    __syncthreads();
  }
#pragma unroll
  for (int i = 0; i < 4; ++i)
#pragma unroll
    for (int j = 0; j < 2; ++j) {
      int row = m0 + wm + i * 16 + lq;
      int col = n0 + wn + j * 16 + quad * 4;
      *(floatx4*)&C[(size_t)row * N + col] = acc[i][j];
    }
}

// ---------------- Flash attention: S-transposed, no-max softmax, intra-block split-K ----------------
// BEST-KNOWN-GOOD (~110-115 us, ~920 TF effective): LDS DMA K dbuf + V 3-buf, deferred-PV,
// in-register P^T transpose, 1 barrier/iter, 4-wave blocks, 2 blocks/CU (8 waves/CU).
// Plateau bracketing (session ledger):
//   R0 setprio: ~0.  R1 in-reg transpose: +8% (conflicts 3.15M->0).  R2/R3 deferred-PV: ~0
//   (both MFMA pools share one matrix pipe).  R4 2-wave blocks: -35% (4 waves/CU: perf is
//   ~linear in waves/CU; 2048 waves is the structural max for this decomposition).
//   R5 V-from-global PV: -33% (per-wave vmcnt stalls at 2 waves/SIMD — same mode as r8;
//   LDS DMA is the only latency structure that works at this occupancy).
__global__ __launch_bounds__(256, 2) void flash_attn(const bf16* __restrict__ QKV,
                                                     const bf16* __restrict__ Vt,
                                                     bf16* __restrict__ O) {
  const int bid = blockIdx.x;
  const int bg = (bid & 7) >> 1;                 // 0..3 -> (b,g), XCD-clustered
  const int b = bg >> 1, g = bg & 1;
  const int qt = ((bid >> 3) << 1) | (bid & 1);  // 0..127
  const int q0 = qt * 32;

  const int tid = threadIdx.x;
  const int w = tid >> 6, lane = tid & 63;
  const int half = w >> 1, wp = w & 1;           // KV-half, index within pair
  const int quad = lane >> 4, lq = lane & 15;

  __shared__ __align__(16) char smem[81920];
  bf16* Ks = (bf16*)smem;            // [kbuf 0..1][half][32*128], chunk c at c^(trow&15)
  bf16* Vs = (bf16*)(smem + 32768);  // [vbuf 0..2][half][128*32], chunk c at c^((drow>>1)&3)

  const bf16* Kgh = QKV + (size_t)b * S * NQKV + H * HD + g * HD + (size_t)half * 2048 * NQKV;
  const bf16* Vgh = Vt + (size_t)(b * HK + g) * HD * S + half * 2048;

  auto stage = [&](int t0, int kbuf, int vbuf) {
    bf16* kd = Ks + (kbuf * 2 + half) * 4096;
    bf16* vd = Vs + (vbuf * 2 + half) * 4096;
#pragma unroll
    for (int i = 0; i < 4; ++i) {
      int ig = wp * 4 + i;                 // 0..7
      int tl = ig * 4 + (lane >> 4);       // 0..31
      int c = (lane & 15) ^ (tl & 15);
      gld_lds16(Kgh + (size_t)(t0 + tl) * NQKV + c * 8, kd + ig * 512);
    }
#pragma unroll
    for (int i = 0; i < 4; ++i) {
      int ig = wp * 4 + i;
      int dl = ig * 16 + (lane >> 2);      // 0..127
      int c = (lane & 3) ^ ((dl >> 1) & 3);
      gld_lds16(Vgh + (size_t)dl * S + t0 + c * 8, vd + ig * 512);
    }
  };

  stage(0, 0, 0);  // prologue: tile 0 -> kbuf 0, vbuf 0

  // Q fragments: B-operand layout (n=lane&15 -> q-row, k=quad*8+j -> d)
  const bf16* Qg = QKV + ((size_t)b * S + q0 + wp * 16 + lq) * NQKV + g * REP * HD;
  bf16x8 qf[3][4];
#pragma unroll
  for (int u = 0; u < 3; ++u)
#pragma unroll
    for (int kk = 0; kk < 4; ++kk)
      qf[u][kk] = *(const bf16x8*)(Qg + u * HD + kk * 32 + quad * 8);

  bf16x8 ones;
#pragma unroll
  for (int j = 0; j < 8; ++j) ones[j] = (short)0x3F80;  // bf16 1.0

  floatx4 o[3][8] = {};
  floatx4 lacc[3] = {};           // denominator via ones-MFMA (all regs = row-sum)
  bf16x8 pf_prev[3];              // P^T B-frags of tile it-1 (deferred-PV state)
  const int sw = (lq >> 1) & 3;   // swizzle key (V layout)

#pragma unroll 2
  for (int it = 0; it < 64; ++it) {
    const int kcur = it & 1;
    __syncthreads();  // K/V[it] staged; V[it-1] still intact (3-buf)
    if (it + 1 < 64) stage((it + 1) * 32, kcur ^ 1, (it + 1) % 3);

    const bf16* ks = Ks + (kcur * 2 + half) * 4096;

    // ---- S^T(it) = K Q^T : kf read once, reused by 3 heads ----
    floatx4 sf[3][2] = {};
    __builtin_amdgcn_s_setprio(1);
#pragma unroll
    for (int tt = 0; tt < 2; ++tt)
#pragma unroll
      for (int kk = 0; kk < 4; ++kk) {
        int c = (kk * 4 + quad) ^ lq;  // t row = tt*16+lq -> key lq
        bf16x8 kf = *(const bf16x8*)&ks[(tt * 16 + lq) * 128 + c * 8];
#pragma unroll
        for (int u = 0; u < 3; ++u) sf[u][tt] = mfma16(kf, qf[u][kk], sf[u][tt]);
      }

    // ---- deferred PV(it-1): independent of QK^T(it) above -> pipes overlap ----
    if (it) {
      const bf16* vs = Vs + ((((it - 1) % 3) * 2) + half) * 4096;
#pragma unroll
      for (int u = 0; u < 3; ++u) lacc[u] = mfma16(ones, pf_prev[u], lacc[u]);
#pragma unroll
      for (int dd = 0; dd < 8; ++dd) {
        bf16x8 vf = *(const bf16x8*)&vs[(dd * 16 + lq) * 32 + ((quad ^ sw) * 8)];
#pragma unroll
        for (int u = 0; u < 3; ++u) o[u][dd] = mfma16(vf, pf_prev[u], o[u][dd]);
      }
    }
    __builtin_amdgcn_s_setprio(0);

    // ---- softmax(it): p = exp2(s); C-layout -> B-frag transpose in-register ----
#pragma unroll
    for (int u = 0; u < 3; ++u) {
      unsigned A0 = pk2(EXP2F(sf[u][0][0]), EXP2F(sf[u][0][1]));
      unsigned A1 = pk2(EXP2F(sf[u][0][2]), EXP2F(sf[u][0][3]));
      unsigned B0 = pk2(EXP2F(sf[u][1][0]), EXP2F(sf[u][1][1]));
      unsigned B1 = pk2(EXP2F(sf[u][1][2]), EXP2F(sf[u][1][3]));
      perm32swap(A0, B0);
      perm16swap(A0, B0);  // A0 = w0 (t=8q+0,1), B0 = w2 (t=8q+4,5)
      perm32swap(A1, B1);
      perm16swap(A1, B1);  // A1 = w1 (t=8q+2,3), B1 = w3 (t=8q+6,7)
      union { unsigned d[4]; bf16x8 v; } pu;
      pu.d[0] = A0; pu.d[1] = A1; pu.d[2] = B0; pu.d[3] = B1;
      pf_prev[u] = pu.v;
    }
  }

  // ---- drain the pipeline: PV(63), V tile 63 lives in slot 63%3 = 0 ----
  {
    const bf16* vs = Vs + (0 * 2 + half) * 4096;
#pragma unroll
    for (int u = 0; u < 3; ++u) lacc[u] = mfma16(ones, pf_prev[u], lacc[u]);
#pragma unroll
    for (int dd = 0; dd < 8; ++dd) {
      bf16x8 vf = *(const bf16x8*)&vs[(dd * 16 + lq) * 32 + ((quad ^ sw) * 8)];
#pragma unroll
      for (int u = 0; u < 3; ++u) o[u][dd] = mfma16(vf, pf_prev[u], o[u][dd]);
    }
  }

  // ---- combine halves in LDS (overlay on Ks/Vs region), then store ----
  __syncthreads();  // all waves done reading K/V
  floatx4* oscr = (floatx4*)smem;           // [pair_slot(0..5)][dd][lane]
  float* lscr = (float*)(smem + 49152);     // [pair_slot][lane]
  if (half == 1) {
#pragma unroll
    for (int u = 0; u < 3; ++u) {
#pragma unroll
      for (int dd = 0; dd < 8; ++dd)
        oscr[((wp * 3 + u) * 8 + dd) * 64 + lane] = o[u][dd];
      lscr[(wp * 3 + u) * 64 + lane] = lacc[u][0];
    }
  }
  __syncthreads();
  if (half == 0) {
    const size_t row = (size_t)b * S + q0 + wp * 16 + lq;
#pragma unroll
    for (int u = 0; u < 3; ++u) {
      float l = lacc[u][0] + lscr[(wp * 3 + u) * 64 + lane];
      float rinv = 1.0f / l;
#pragma unroll
      for (int dd = 0; dd < 8; ++dd) {
        floatx4 oc = o[u][dd] + oscr[((wp * 3 + u) * 8 + dd) * 64 + lane];
        uint2 st;
        st.x = pk2(oc[0] * rinv, oc[1] * rinv);
        st.y = pk2(oc[2] * rinv, oc[3] * rinv);
        int col = (g * REP + u) * HD + dd * 16 + quad * 4;
        *(uint2*)&O[row * (H * HD) + col] = st;
      }
    }
  }
}

// ---------------- launch ----------------
static inline size_t al256(size_t x) { return (x + 255) & ~size_t(255); }

extern "C" void kernel_launch(void* const* d_in, const int* in_sizes, int n_in,
                              void* d_out, int out_size, void* d_ws, size_t ws_size,
                              hipStream_t stream) {
  const float* x  = (const float*)d_in[0];
  const float* wq = (const float*)d_in[1];
  const float* wk = (const float*)d_in[2];
  const float* wv = (const float*)d_in[3];
  const float* wo = (const float*)d_in[4];
  float* out = (float*)d_out;

  char* w = (char*)d_ws;
  size_t off = 0;
  auto carve = [&](size_t elems) {
    bf16* p = (bf16*)(w + off);
    off = al256(off + elems * sizeof(bf16));
    return p;
  };
  bf16* xb    = carve((size_t)M_ROWS * D);
  bf16* wqkvb = carve((size_t)NQKV * D);  // wq(768) | wk(256) | wv(256) rows
  bf16* wob   = carve((size_t)D * (H * HD));
  bf16* QKVb  = carve((size_t)M_ROWS * NQKV);
  bf16* Vtb   = carve((size_t)M_ROWS * (HK * HD));
  bf16* Ab    = carve((size_t)M_ROWS * (H * HD));

  // (1/sqrt(128)) * log2(e), folded into wq: scores come out in log2 domain
  const float qscale = 0.1275174465f;

  cvt_all<<<(int)(E_WO / 1024), 256, 0, stream>>>(x, wq, wk, wv, wo, xb, wqkvb, wob, qscale);

  // fused QKV projection: [8192,768] x [1280,768]^T, single 640-block launch;
  // Q/K -> packed C stores, V -> Vt transposed (QKVb V-cols never read)
  gemm_qkv<<<dim3(M_ROWS / 128, NQKV / 128), 256, 0, stream>>>(
      xb, wqkvb, QKVb, Vtb, M_ROWS, NQKV, D);

  flash_attn<<<512, 256, 0, stream>>>(QKVb, Vtb, Ab);

  // out projection: 128x64 tiles -> 768 blocks (exactly 3/CU x 256 CUs, 12 waves/CU)
  gemm_out<<<dim3(M_ROWS / 128, D / 64), 256, 0, stream>>>(
      Ab, wob, out, M_ROWS, D, H * HD);
}

// Round 11
// 220.674 us; speedup vs baseline: 1.6327x; 1.0120x over previous
//
#include <hip/hip_runtime.h>
#include <hip/hip_bf16.h>
#include <type_traits>

using bf16 = __hip_bfloat16;
typedef __attribute__((ext_vector_type(8))) short bf16x8;   // 8 bf16 (4 VGPRs) — MFMA A/B frag
typedef __attribute__((ext_vector_type(4))) float floatx4;  // MFMA C/D frag

static constexpr int Bb = 2, S = 4096, D = 768, H = 6, HK = 2, HD = 128, REP = 3;
static constexpr int M_ROWS = Bb * S;   // 8192
static constexpr int NQKV = 1280;       // fused projection width: 768 Q + 256 K + 256 V

__device__ __forceinline__ floatx4 mfma16(bf16x8 a, bf16x8 b, floatx4 c) {
  return __builtin_amdgcn_mfma_f32_16x16x32_bf16(a, b, c, 0, 0, 0);
}

// async global->LDS, 16B/lane; LDS dest = wave-uniform base + lane*16
__device__ __forceinline__ void gld_lds16(const bf16* g, bf16* l) {
  __builtin_amdgcn_global_load_lds(
      (const __attribute__((address_space(1))) unsigned int*)g,
      (__attribute__((address_space(3))) unsigned int*)l, 16, 0, 0);
}

#if defined(__has_builtin)
#if __has_builtin(__builtin_amdgcn_exp2f)
#define EXP2F(x) __builtin_amdgcn_exp2f(x)
#endif
#endif
#ifndef EXP2F
#define EXP2F(x) exp2f(x)
#endif

// pack two fp32 -> 2x bf16 (round-half-up): bias + one v_perm_b32
__device__ __forceinline__ unsigned pk2(float a, float b) {
  unsigned ua = __builtin_bit_cast(unsigned, a) + 0x8000u;
  unsigned ub = __builtin_bit_cast(unsigned, b) + 0x8000u;
#if defined(__has_builtin) && __has_builtin(__builtin_amdgcn_perm)
  return __builtin_amdgcn_perm(ub, ua, 0x07060302);  // {ub.hi16, ua.hi16}
#else
  return (ua >> 16) | (ub & 0xffff0000u);
#endif
}

// gfx950 cross-lane half-swaps (register-only, VALU pipe — no LDS, no waitcnt):
// perm32swap(a,b): a' = [a.q0,a.q1,b.q0,b.q1], b' = [a.q2,a.q3,b.q2,b.q3]   (by 16-lane quads)
// perm16swap(a,b): a' = [a.q0,b.q0,a.q2,b.q2], b' = [a.q1,b.q1,a.q3,b.q3]
__device__ __forceinline__ void perm32swap(unsigned& a, unsigned& b) {
  asm volatile("v_permlane32_swap_b32 %0, %1" : "+v"(a), "+v"(b));
}
__device__ __forceinline__ void perm16swap(unsigned& a, unsigned& b) {
  asm volatile("v_permlane16_swap_b32 %0, %1" : "+v"(a), "+v"(b));
}

// ---------------- fused fp32 -> bf16 convert for all 5 inputs ----------------
// R8/R9 LESSON: fusing the x-conversion into gemm_qkv A-staging LOSES (spill at 175us, or
// +28us spill-free: reg-staging exposes serial VMEM latency that 3 blocks/CU can't hide;
// fire-and-forget global_load_lds DMA is the only staging structure that works there).
static constexpr size_t E_X  = (size_t)M_ROWS * D;                 // 6291456
static constexpr size_t E_WQ = E_X + (size_t)H * HD * D;           // +589824
static constexpr size_t E_WK = E_WQ + (size_t)HK * HD * D;         // +196608
static constexpr size_t E_WV = E_WK + (size_t)HK * HD * D;         // +196608
static constexpr size_t E_WO = E_WV + (size_t)D * H * HD;          // +589824 = 7864320

__global__ __launch_bounds__(256) void cvt_all(const float* __restrict__ x,
                                               const float* __restrict__ wq,
                                               const float* __restrict__ wk,
                                               const float* __restrict__ wv,
                                               const float* __restrict__ wo,
                                               bf16* __restrict__ xb,
                                               bf16* __restrict__ wqkvb,
                                               bf16* __restrict__ wob, float qscale) {
  size_t i = ((size_t)blockIdx.x * 256 + threadIdx.x) * 4;
  const float* src;
  bf16* dst;
  float s = 1.f;
  size_t off;
  if (i < E_X)        { src = x;  dst = xb;                 off = i; }
  else if (i < E_WQ)  { src = wq; dst = wqkvb;              off = i - E_X; s = qscale; }
  else if (i < E_WK)  { src = wk; dst = wqkvb + 589824;     off = i - E_WQ; }
  else if (i < E_WV)  { src = wv; dst = wqkvb + 786432;     off = i - E_WK; }
  else                { src = wo; dst = wob;                off = i - E_WV; }
  float4 v = *(const float4*)(src + off);
  uint2 st;
  st.x = pk2(v.x * s, v.y * s);
  st.y = pk2(v.z * s, v.w * s);
  *(uint2*)(dst + off) = st;
}

// ---------------- fused QKV projection GEMM: single 640-block launch, dual epilogue ------------
// C[M,N] = A[M,K] @ W[N,K]^T. 128x128 tile, BK=64, global_load_lds width-16, XOR-swizzled LDS.
// Merged single launch (R6: splitting cost occupancy + launch + A re-read = +8us).
// Dual epilogue, block-uniform branch on n0 (OUTSIDE the K-loop — R8: in-loop branch spills acc):
//   n0 < 1024 (Q/K): SWAPPED mfma16(wf, af) -> transposed fragment -> packed uint2 stores.
//   n0 >= 1024 (V): original order -> verified col-XOR LDS transpose -> Vt[b][g][d][t].
// Dispatch: bid = m + 64*n -> same-m blocks land on the SAME XCD -> A panels L2-local.
__global__ __launch_bounds__(256, 3) void gemm_qkv(const bf16* __restrict__ A,
                                                   const bf16* __restrict__ W,
                                                   bf16* __restrict__ C,
                                                   bf16* __restrict__ Vt,
                                                   int M, int N, int K) {
  const int tid = threadIdx.x;
  const int wave = tid >> 6, lane = tid & 63;
  const int quad = lane >> 4, lq = lane & 15;
  const int m0 = blockIdx.x * 128, n0 = blockIdx.y * 128;
  const int wm = (wave & 1) * 64, wn = (wave >> 1) * 64;

  __shared__ __align__(16) bf16 As[128 * 64];  // 16 KB
  __shared__ __align__(16) bf16 Ws[128 * 64];  // 16 KB

  floatx4 acc[4][4] = {};

  const int srow = lane >> 3, sc = lane & 7;  // staging: 8 rows x 8 chunks per issue

  if (n0 < 1024) {
    // ---------------- Q/K path: swapped operands, packed epilogue ----------------
    for (int k0 = 0; k0 < K; k0 += 64) {
#pragma unroll
      for (int i = 0; i < 4; ++i) {
        int ig = wave * 4 + i;               // 0..15
        int r = ig * 8 + srow;               // 0..127
        int c = sc ^ (r & 7);
        gld_lds16(&A[(size_t)(m0 + r) * K + k0 + c * 8], &As[ig * 512]);
        gld_lds16(&W[(size_t)(n0 + r) * K + k0 + c * 8], &Ws[ig * 512]);
      }
      __syncthreads();
#pragma unroll
      for (int kh = 0; kh < 2; ++kh) {
        bf16x8 af[4], wf[4];
#pragma unroll
        for (int i = 0; i < 4; ++i) {
          int ra = wm + i * 16 + lq, rw = wn + i * 16 + lq;
          af[i] = *(const bf16x8*)&As[ra * 64 + (((kh * 4 + quad) ^ (ra & 7)) * 8)];
          wf[i] = *(const bf16x8*)&Ws[rw * 64 + (((kh * 4 + quad) ^ (rw & 7)) * 8)];
        }
#pragma unroll
        for (int i = 0; i < 4; ++i)
#pragma unroll
          for (int j = 0; j < 4; ++j) acc[i][j] = mfma16(wf[j], af[i], acc[i][j]);  // swapped
      }
      __syncthreads();
    }
    // packed epilogue: lane(quad,lq) -> row m0+wm+i*16+lq, cols n0+wn+j*16+quad*4 .. +3
#pragma unroll
    for (int i = 0; i < 4; ++i)
#pragma unroll
      for (int j = 0; j < 4; ++j) {
        uint2 st;
        st.x = pk2(acc[i][j][0], acc[i][j][1]);
        st.y = pk2(acc[i][j][2], acc[i][j][3]);
        int row = m0 + wm + i * 16 + lq;
        int col = n0 + wn + j * 16 + quad * 4;
        *(uint2*)&C[(size_t)row * N + col] = st;
      }
    return;
  }

  // ---------------- V path: original order, Vt-transpose epilogue ----------------
  for (int k0 = 0; k0 < K; k0 += 64) {
#pragma unroll
    for (int i = 0; i < 4; ++i) {
      int ig = wave * 4 + i;               // 0..15
      int r = ig * 8 + srow;               // 0..127
      int c = sc ^ (r & 7);
      gld_lds16(&A[(size_t)(m0 + r) * K + k0 + c * 8], &As[ig * 512]);
      gld_lds16(&W[(size_t)(n0 + r) * K + k0 + c * 8], &Ws[ig * 512]);
    }
    __syncthreads();
#pragma unroll
    for (int kh = 0; kh < 2; ++kh) {
      bf16x8 af[4], wf[4];
#pragma unroll
      for (int i = 0; i < 4; ++i) {
        int ra = wm + i * 16 + lq, rw = wn + i * 16 + lq;
        af[i] = *(const bf16x8*)&As[ra * 64 + (((kh * 4 + quad) ^ (ra & 7)) * 8)];
        wf[i] = *(const bf16x8*)&Ws[rw * 64 + (((kh * 4 + quad) ^ (rw & 7)) * 8)];
      }
#pragma unroll
      for (int i = 0; i < 4; ++i)
#pragma unroll
        for (int j = 0; j < 4; ++j) acc[i][j] = mfma16(af[i], wf[j], acc[i][j]);
    }
    __syncthreads();
  }

  // col-XOR-swizzled LDS transpose, then coalesced b128 stores to Vt[b][g][d][t]
  bf16* tb = (wave < 2 ? As : Ws) + (wave & 1) * 4096;
  char* tc = (char*)tb;
#pragma unroll
  for (int i = 0; i < 4; ++i)
#pragma unroll
    for (int j = 0; j < 4; ++j) {
      uint2 st;
      st.x = pk2(acc[i][j][0], acc[i][j][1]);
      st.y = pk2(acc[i][j][2], acc[i][j][3]);
      int col = j * 16 + lq;
      int cc = (i * 2 + (quad >> 1)) ^ (col & 7);
      *(uint2*)(tc + col * 128 + cc * 16 + (quad & 1) * 8) = st;
    }
  const int b = m0 >> 12;  // uniform per block (128-row tiles never cross S)
  const int dd_off = lane >> 3, schunk = lane & 7;
  const int sbase = (m0 & 4095) + wm + schunk * 8;
#pragma unroll
  for (int e = 0; e < 8; ++e) {
    int cl = e * 8 + dd_off;                      // local col 0..63
    int col = (n0 - 1024) + wn + cl;              // 0..255
    int gg = col >> 7, dd = col & 127;
    bf16x8 vv = *(const bf16x8*)(tc + cl * 128 + ((schunk ^ (cl & 7)) * 16));
    *(bf16x8*)&Vt[((size_t)(b * HK + gg) * HD + dd) * S + sbase] = vv;
  }
}

// ---------------- out-projection GEMM: 128x64 tile, swapped operands + float4 stores ----------------
// 128x64 tiles -> 768 blocks = exactly 3/CU x 256 CUs, 12 waves/CU, single full round.
__global__ __launch_bounds__(256, 3) void gemm_out(const bf16* __restrict__ A,
                                                   const bf16* __restrict__ W,
                                                   float* __restrict__ C,
                                                   int M, int N, int K) {
  const int tid = threadIdx.x;
  const int wave = tid >> 6, lane = tid & 63;
  const int quad = lane >> 4, lq = lane & 15;
  const int m0 = blockIdx.x * 128, n0 = blockIdx.y * 64;
  const int wm = (wave & 1) * 64, wn = (wave >> 1) * 32;

  __shared__ __align__(16) bf16 As[128 * 64];  // 16 KB
  __shared__ __align__(16) bf16 Ws[64 * 64];   // 8 KB

  floatx4 acc[4][2] = {};

  const int srow = lane >> 3, sc = lane & 7;  // staging: 8 rows x 8 chunks per issue

  for (int k0 = 0; k0 < K; k0 += 64) {
#pragma unroll
    for (int i = 0; i < 4; ++i) {
      int ig = wave * 4 + i;               // 0..15
      int r = ig * 8 + srow;               // 0..127
      int c = sc ^ (r & 7);
      gld_lds16(&A[(size_t)(m0 + r) * K + k0 + c * 8], &As[ig * 512]);
    }
#pragma unroll
    for (int i = 0; i < 2; ++i) {
      int ig = wave * 2 + i;               // 0..7
      int r = ig * 8 + srow;               // 0..63
      int c = sc ^ (r & 7);
      gld_lds16(&W[(size_t)(n0 + r) * K + k0 + c * 8], &Ws[ig * 512]);
    }
    __syncthreads();
#pragma unroll
    for (int kh = 0; kh < 2; ++kh) {
      bf16x8 af[4], wf[2];
#pragma unroll
      for (int i = 0; i < 4; ++i) {
        int ra = wm + i * 16 + lq;
        af[i] = *(const bf16x8*)&As[ra * 64 + (((kh * 4 + quad) ^ (ra & 7)) * 8)];
      }
#pragma unroll
      for (int j = 0; j < 2; ++j) {
        int rw = wn + j * 16 + lq;
        wf[j] = *(const bf16x8*)&Ws[rw * 64 + (((kh * 4 + quad) ^ (rw & 7)) * 8)];
      }
#pragma unroll
      for (int i = 0; i < 4; ++i)
#pragma unroll
        for (int j = 0; j < 2; ++j) acc[i][j] = mfma16(wf[j], af[i], acc[i][j]);  // swapped
    }
    __syncthreads();
  }
#pragma unroll
  for (int i = 0; i < 4; ++i)
#pragma unroll
    for (int j = 0; j < 2; ++j) {
      int row = m0 + wm + i * 16 + lq;
      int col = n0 + wn + j * 16 + quad * 4;
      *(floatx4*)&C[(size_t)row * N + col] = acc[i][j];
    }
}

// ---------------- Flash attention: S-transposed, no-max softmax, intra-block split-K ----------------
// BEST-KNOWN-GOOD structure (~111 us): LDS DMA K dbuf + V 3-buf, deferred-PV, in-register
// P^T transpose, 1 barrier/iter, 4-wave blocks, 2 blocks/CU (8 waves/CU).
// R11: hoisted staging pointers (R4's validated piece, finally isolated): stage() was
// recomputing 16 lane-dependent 64-bit addresses per iter ((t0+tl)*NQKV, dl*S+t0 — v_mul+
// 64b add chains, ~100-160 VALU ops/iter/wave, comparable to the whole softmax). Now 8
// persistent pointers advanced by constant strides (+32*NQKV, +32) = 16 VALU adds/iter.
// +16 VGPRs (occupancy is LDS-limited at 2 blocks/CU -> free). Addresses bit-identical.
// Plateau ledger: R0 setprio ~0; R1 in-reg transpose +8%; R2/R3 deferred-PV ~0; R4 2-wave
// blocks -35% (waves/CU is the lever, 2048 waves = structural max); R5 V-from-global -33%
// (vmcnt stalls at 2 waves/SIMD; LDS DMA is the only staging that works here).
__global__ __launch_bounds__(256, 2) void flash_attn(const bf16* __restrict__ QKV,
                                                     const bf16* __restrict__ Vt,
                                                     bf16* __restrict__ O) {
  const int bid = blockIdx.x;
  const int bg = (bid & 7) >> 1;                 // 0..3 -> (b,g), XCD-clustered
  const int b = bg >> 1, g = bg & 1;
  const int qt = ((bid >> 3) << 1) | (bid & 1);  // 0..127
  const int q0 = qt * 32;

  const int tid = threadIdx.x;
  const int w = tid >> 6, lane = tid & 63;
  const int half = w >> 1, wp = w & 1;           // KV-half, index within pair
  const int quad = lane >> 4, lq = lane & 15;

  __shared__ __align__(16) char smem[81920];
  bf16* Ks = (bf16*)smem;            // [kbuf 0..1][half][32*128], chunk c at c^(trow&15)
  bf16* Vs = (bf16*)(smem + 32768);  // [vbuf 0..2][half][128*32], chunk c at c^((drow>>1)&3)

  const bf16* Kgh = QKV + (size_t)b * S * NQKV + H * HD + g * HD + (size_t)half * 2048 * NQKV;
  const bf16* Vgh = Vt + (size_t)(b * HK + g) * HD * S + half * 2048;

  // hoisted staging pointers: lane-dependent bases, advanced by constant stride per tile
  const bf16* kp[4];
  const bf16* vp[4];
#pragma unroll
  for (int i = 0; i < 4; ++i) {
    int tl = (wp * 4 + i) * 4 + (lane >> 4);     // 0..31
    int c = (lane & 15) ^ (tl & 15);
    kp[i] = Kgh + (size_t)tl * NQKV + c * 8;
  }
#pragma unroll
  for (int i = 0; i < 4; ++i) {
    int dl = (wp * 4 + i) * 16 + (lane >> 2);    // 0..127
    int c = (lane & 3) ^ ((dl >> 1) & 3);
    vp[i] = Vgh + (size_t)dl * S + c * 8;
  }

  auto stage = [&](int kbuf, int vbuf) {
    bf16* kd = Ks + (kbuf * 2 + half) * 4096;
    bf16* vd = Vs + (vbuf * 2 + half) * 4096;
#pragma unroll
    for (int i = 0; i < 4; ++i) gld_lds16(kp[i], kd + (wp * 4 + i) * 512);
#pragma unroll
    for (int i = 0; i < 4; ++i) gld_lds16(vp[i], vd + (wp * 4 + i) * 512);
#pragma unroll
    for (int i = 0; i < 4; ++i) { kp[i] += 32 * NQKV; vp[i] += 32; }
  };

  stage(0, 0);  // prologue: tile 0 -> kbuf 0, vbuf 0

  // Q fragments: B-operand layout (n=lane&15 -> q-row, k=quad*8+j -> d)
  const bf16* Qg = QKV + ((size_t)b * S + q0 + wp * 16 + lq) * NQKV + g * REP * HD;
  bf16x8 qf[3][4];
#pragma unroll
  for (int u = 0; u < 3; ++u)
#pragma unroll
    for (int kk = 0; kk < 4; ++kk)
      qf[u][kk] = *(const bf16x8*)(Qg + u * HD + kk * 32 + quad * 8);

  bf16x8 ones;
#pragma unroll
  for (int j = 0; j < 8; ++j) ones[j] = (short)0x3F80;  // bf16 1.0

  floatx4 o[3][8] = {};
  floatx4 lacc[3] = {};           // denominator via ones-MFMA (all regs = row-sum)
  bf16x8 pf_prev[3];              // P^T B-frags of tile it-1 (deferred-PV state)
  const int sw = (lq >> 1) & 3;   // swizzle key (V layout)

#pragma unroll 2
  for (int it = 0; it < 64; ++it) {
    const int kcur = it & 1;
    __syncthreads();  // K/V[it] staged; V[it-1] still intact (3-buf)
    if (it + 1 < 64) stage(kcur ^ 1, (it + 1) % 3);

    const bf16* ks = Ks + (kcur * 2 + half) * 4096;

    // ---- S^T(it) = K Q^T : kf read once, reused by 3 heads ----
    floatx4 sf[3][2] = {};
    __builtin_amdgcn_s_setprio(1);
#pragma unroll
    for (int tt = 0; tt < 2; ++tt)
#pragma unroll
      for (int kk = 0; kk < 4; ++kk) {
        int c = (kk * 4 + quad) ^ lq;  // t row = tt*16+lq -> key lq
        bf16x8 kf = *(const bf16x8*)&ks[(tt * 16 + lq) * 128 + c * 8];
#pragma unroll
        for (int u = 0; u < 3; ++u) sf[u][tt] = mfma16(kf, qf[u][kk], sf[u][tt]);
      }

    // ---- deferred PV(it-1): independent of QK^T(it) above -> pipes overlap ----
    if (it) {
      const bf16* vs = Vs + ((((it - 1) % 3) * 2) + half) * 4096;
#pragma unroll
      for (int u = 0; u < 3; ++u) lacc[u] = mfma16(ones, pf_prev[u], lacc[u]);
#pragma unroll
      for (int dd = 0; dd < 8; ++dd) {
        bf16x8 vf = *(const bf16x8*)&vs[(dd * 16 + lq) * 32 + ((quad ^ sw) * 8)];
#pragma unroll
        for (int u = 0; u < 3; ++u) o[u][dd] = mfma16(vf, pf_prev[u], o[u][dd]);
      }
    }
    __builtin_amdgcn_s_setprio(0);

    // ---- softmax(it): p = exp2(s); C-layout -> B-frag transpose in-register ----
#pragma unroll
    for (int u = 0; u < 3; ++u) {
      unsigned A0 = pk2(EXP2F(sf[u][0][0]), EXP2F(sf[u][0][1]));
      unsigned A1 = pk2(EXP2F(sf[u][0][2]), EXP2F(sf[u][0][3]));
      unsigned B0 = pk2(EXP2F(sf[u][1][0]), EXP2F(sf[u][1][1]));
      unsigned B1 = pk2(EXP2F(sf[u][1][2]), EXP2F(sf[u][1][3]));
      perm32swap(A0, B0);
      perm16swap(A0, B0);  // A0 = w0 (t=8q+0,1), B0 = w2 (t=8q+4,5)
      perm32swap(A1, B1);
      perm16swap(A1, B1);  // A1 = w1 (t=8q+2,3), B1 = w3 (t=8q+6,7)
      union { unsigned d[4]; bf16x8 v; } pu;
      pu.d[0] = A0; pu.d[1] = A1; pu.d[2] = B0; pu.d[3] = B1;
      pf_prev[u] = pu.v;
    }
  }

  // ---- drain the pipeline: PV(63), V tile 63 lives in slot 63%3 = 0 ----
  {
    const bf16* vs = Vs + (0 * 2 + half) * 4096;
#pragma unroll
    for (int u = 0; u < 3; ++u) lacc[u] = mfma16(ones, pf_prev[u], lacc[u]);
#pragma unroll
    for (int dd = 0; dd < 8; ++dd) {
      bf16x8 vf = *(const bf16x8*)&vs[(dd * 16 + lq) * 32 + ((quad ^ sw) * 8)];
#pragma unroll
      for (int u = 0; u < 3; ++u) o[u][dd] = mfma16(vf, pf_prev[u], o[u][dd]);
    }
  }

  // ---- combine halves in LDS (overlay on Ks/Vs region), then store ----
  __syncthreads();  // all waves done reading K/V
  floatx4* oscr = (floatx4*)smem;           // [pair_slot(0..5)][dd][lane]
  float* lscr = (float*)(smem + 49152);     // [pair_slot][lane]
  if (half == 1) {
#pragma unroll
    for (int u = 0; u < 3; ++u) {
#pragma unroll
      for (int dd = 0; dd < 8; ++dd)
        oscr[((wp * 3 + u) * 8 + dd) * 64 + lane] = o[u][dd];
      lscr[(wp * 3 + u) * 64 + lane] = lacc[u][0];
    }
  }
  __syncthreads();
  if (half == 0) {
    const size_t row = (size_t)b * S + q0 + wp * 16 + lq;
#pragma unroll
    for (int u = 0; u < 3; ++u) {
      float l = lacc[u][0] + lscr[(wp * 3 + u) * 64 + lane];
      float rinv = 1.0f / l;
#pragma unroll
      for (int dd = 0; dd < 8; ++dd) {
        floatx4 oc = o[u][dd] + oscr[((wp * 3 + u) * 8 + dd) * 64 + lane];
        uint2 st;
        st.x = pk2(oc[0] * rinv, oc[1] * rinv);
        st.y = pk2(oc[2] * rinv, oc[3] * rinv);
        int col = (g * REP + u) * HD + dd * 16 + quad * 4;
        *(uint2*)&O[row * (H * HD) + col] = st;
      }
    }
  }
}

// ---------------- launch ----------------
static inline size_t al256(size_t x) { return (x + 255) & ~size_t(255); }

extern "C" void kernel_launch(void* const* d_in, const int* in_sizes, int n_in,
                              void* d_out, int out_size, void* d_ws, size_t ws_size,
                              hipStream_t stream) {
  const float* x  = (const float*)d_in[0];
  const float* wq = (const float*)d_in[1];
  const float* wk = (const float*)d_in[2];
  const float* wv = (const float*)d_in[3];
  const float* wo = (const float*)d_in[4];
  float* out = (float*)d_out;

  char* w = (char*)d_ws;
  size_t off = 0;
  auto carve = [&](size_t elems) {
    bf16* p = (bf16*)(w + off);
    off = al256(off + elems * sizeof(bf16));
    return p;
  };
  bf16* xb    = carve((size_t)M_ROWS * D);
  bf16* wqkvb = carve((size_t)NQKV * D);  // wq(768) | wk(256) | wv(256) rows
  bf16* wob   = carve((size_t)D * (H * HD));
  bf16* QKVb  = carve((size_t)M_ROWS * NQKV);
  bf16* Vtb   = carve((size_t)M_ROWS * (HK * HD));
  bf16* Ab    = carve((size_t)M_ROWS * (H * HD));

  // (1/sqrt(128)) * log2(e), folded into wq: scores come out in log2 domain
  const float qscale = 0.1275174465f;

  cvt_all<<<(int)(E_WO / 1024), 256, 0, stream>>>(x, wq, wk, wv, wo, xb, wqkvb, wob, qscale);

  // fused QKV projection: [8192,768] x [1280,768]^T, single 640-block launch;
  // Q/K -> packed C stores, V -> Vt transposed (QKVb V-cols never read)
  gemm_qkv<<<dim3(M_ROWS / 128, NQKV / 128), 256, 0, stream>>>(
      xb, wqkvb, QKVb, Vtb, M_ROWS, NQKV, D);

  flash_attn<<<512, 256, 0, stream>>>(QKVb, Vtb, Ab);

  // out projection: 128x64 tiles -> 768 blocks (exactly 3/CU x 256 CUs, 12 waves/CU)
  gemm_out<<<dim3(M_ROWS / 128, D / 64), 256, 0, stream>>>(
      Ab, wob, out, M_ROWS, D, H * HD);
}